// Round 1
// baseline (3706.693 us; speedup 1.0000x reference)
//
#include <hip/hip_runtime.h>
#include <cstddef>

#define U_CNT 20000
#define I_CNT 15000
#define N_CNT 35000
#define A_CNT 2048
#define NC_K  2048
#define EAU   300000
#define EUI   300000
#define ER    60000

static const size_t UD_N = (size_t)U_CNT * 64;
static const size_t ID_N = (size_t)I_CNT * 64;

__device__ __forceinline__ float4 ld4(const float* p){ return *reinterpret_cast<const float4*>(p); }
__device__ __forceinline__ void st4(float* p, float4 v){ *reinterpret_cast<float4*>(p) = v; }
__device__ __forceinline__ float4 mul4(float4 a, float4 b){ return make_float4(a.x*b.x, a.y*b.y, a.z*b.z, a.w*b.w); }
__device__ __forceinline__ float4 add4(float4 a, float4 b){ return make_float4(a.x+b.x, a.y+b.y, a.z+b.z, a.w+b.w); }
__device__ __forceinline__ float4 fmas4(float s, float4 b, float4 c){
  return make_float4(fmaf(s,b.x,c.x), fmaf(s,b.y,c.y), fmaf(s,b.z,c.z), fmaf(s,b.w,c.w));
}

// ---------------------------------------------------------------------------
// C[M,64] = A[M,K] @ W[K,64] (+ bias[64]) (* mulp[M,64])   (bias/mulp optional)
// BM=64, BN=64, BK=32; 256 threads; 4x4 micro-tile per thread.
// ---------------------------------------------------------------------------
__global__ __launch_bounds__(256) void gemm64(
    const float* __restrict__ A, int M, int K,
    const float* __restrict__ W, const float* __restrict__ bias,
    const float* __restrict__ mulp, float* __restrict__ C)
{
  __shared__ float As[64][36];   // +4 pad keeps float4 alignment, breaks pow2 stride
  __shared__ float Ws[32][64];
  const int t  = threadIdx.x;
  const int r0 = blockIdx.x * 64;
  const int ty = t >> 4, tx = t & 15;
  float4 acc0 = make_float4(0,0,0,0), acc1 = acc0, acc2 = acc0, acc3 = acc0;

  for (int k0 = 0; k0 < K; k0 += 32) {
    __syncthreads();
    #pragma unroll
    for (int i = 0; i < 2; ++i) {
      int f = t + i*256;
      int row = f >> 3, ca = (f & 7) << 2;      // A tile: 64 rows x 32 cols
      float4 v = make_float4(0.f,0.f,0.f,0.f);
      int r = r0 + row;
      if (r < M) v = ld4(&A[(size_t)r*K + k0 + ca]);
      st4(&As[row][ca], v);
      int kk = f >> 4, cb = (f & 15) << 2;      // W tile: 32 rows x 64 cols
      st4(&Ws[kk][cb], ld4(&W[(size_t)(k0+kk)*64 + cb]));
    }
    __syncthreads();
    #pragma unroll
    for (int kk = 0; kk < 32; kk += 4) {
      float4 a0 = ld4(&As[ty*4+0][kk]);
      float4 a1 = ld4(&As[ty*4+1][kk]);
      float4 a2 = ld4(&As[ty*4+2][kk]);
      float4 a3 = ld4(&As[ty*4+3][kk]);
      float a0v[4] = {a0.x,a0.y,a0.z,a0.w};
      float a1v[4] = {a1.x,a1.y,a1.z,a1.w};
      float a2v[4] = {a2.x,a2.y,a2.z,a2.w};
      float a3v[4] = {a3.x,a3.y,a3.z,a3.w};
      #pragma unroll
      for (int j = 0; j < 4; ++j) {
        float4 wv = ld4(&Ws[kk+j][tx<<2]);
        acc0 = fmas4(a0v[j], wv, acc0);
        acc1 = fmas4(a1v[j], wv, acc1);
        acc2 = fmas4(a2v[j], wv, acc2);
        acc3 = fmas4(a3v[j], wv, acc3);
      }
    }
  }

  float4 bv = make_float4(0,0,0,0);
  if (bias) bv = ld4(&bias[tx<<2]);
  float4 accs[4] = {acc0,acc1,acc2,acc3};
  #pragma unroll
  for (int i = 0; i < 4; ++i) {
    int r = r0 + ty*4 + i;
    if (r < M) {
      float4 v = add4(accs[i], bv);
      size_t o = (size_t)r*64 + (tx<<2);
      if (mulp) v = mul4(v, ld4(&mulp[o]));
      st4(&C[o], v);
    }
  }
}

// acc[dst[e]] += msg[src[e]]           (16 threads per edge, float4 each)
__global__ __launch_bounds__(256) void scatter_plain(
    const float* __restrict__ msg, const int* __restrict__ src,
    const int* __restrict__ dst, int E, float* __restrict__ acc)
{
  int gid = blockIdx.x*256 + threadIdx.x;
  if (gid >= E*16) return;
  int e = gid >> 4, q = (gid & 15) << 2;
  int s = src[e], d = dst[e];
  float4 v = ld4(&msg[(size_t)s*64 + q]);
  float* p = &acc[(size_t)d*64 + q];
  atomicAdd(p+0, v.x); atomicAdd(p+1, v.y); atomicAdd(p+2, v.z); atomicAdd(p+3, v.w);
}

// acc[dst[e]] += a[src[e]] (* b[src[e]]) * sigmoid(emb[rating[e]])
__global__ __launch_bounds__(256) void scatter_sig(
    const float* __restrict__ a, const float* __restrict__ b,
    const int* __restrict__ src, const int* __restrict__ dst,
    const int* __restrict__ rating, const float* __restrict__ emb,
    int E, float* __restrict__ acc)
{
  int gid = blockIdx.x*256 + threadIdx.x;
  if (gid >= E*16) return;
  int e = gid >> 4, q = (gid & 15) << 2;
  int s = src[e], d = dst[e], r = rating[e];
  float4 v = ld4(&a[(size_t)s*64 + q]);
  if (b) v = mul4(v, ld4(&b[(size_t)s*64 + q]));
  float4 ev = ld4(&emb[(size_t)r*64 + q]);
  float4 sg = make_float4(1.f/(1.f+__expf(-ev.x)), 1.f/(1.f+__expf(-ev.y)),
                          1.f/(1.f+__expf(-ev.z)), 1.f/(1.f+__expf(-ev.w)));
  v = mul4(v, sg);
  float* p = &acc[(size_t)d*64 + q];
  atomicAdd(p+0, v.x); atomicAdd(p+1, v.y); atomicAdd(p+2, v.z); atomicAdd(p+3, v.w);
}

// accA[dst] += (w[src]+re[e])*cui[src];  accB[dst] += re[e]*cui[src]
__global__ __launch_bounds__(256) void scatter_fe5(
    const float* __restrict__ re, const float* __restrict__ w,
    const float* __restrict__ cui, const int* __restrict__ src,
    const int* __restrict__ dst, int E,
    float* __restrict__ accA, float* __restrict__ accB)
{
  int gid = blockIdx.x*256 + threadIdx.x;
  if (gid >= E*16) return;
  int e = gid >> 4, q = (gid & 15) << 2;
  int s = src[e], d = dst[e];
  float4 rv = ld4(&re[(size_t)e*64 + q]);
  float4 wv = ld4(&w[(size_t)s*64 + q]);
  float4 cv = ld4(&cui[(size_t)s*64 + q]);
  float4 m1 = mul4(add4(wv, rv), cv);
  float4 m2 = mul4(rv, cv);
  float* pA = &accA[(size_t)d*64 + q];
  float* pB = &accB[(size_t)d*64 + q];
  atomicAdd(pA+0,m1.x); atomicAdd(pA+1,m1.y); atomicAdd(pA+2,m1.z); atomicAdd(pA+3,m1.w);
  atomicAdd(pB+0,m2.x); atomicAdd(pB+1,m2.y); atomicAdd(pB+2,m2.z); atomicAdd(pB+3,m2.w);
}

// msg = (mask*(h*ca) + (1-mask)*fe) * cui     (in-place h==msg is safe)
__global__ __launch_bounds__(256) void blend_msg(
    const float* __restrict__ h, const float* __restrict__ ca,
    const float* __restrict__ fe, const float* __restrict__ mask,
    const float* __restrict__ cui, float* __restrict__ msg, int M)
{
  int gid = blockIdx.x*256 + threadIdx.x;
  if (gid >= M*16) return;
  int n = gid >> 4, q = (gid & 15) << 2;
  size_t o = (size_t)n*64 + q;
  float m = mask[n], im = 1.f - m;
  float4 hv = ld4(&h[o]), cav = ld4(&ca[o]), fev = ld4(&fe[o]), cv = ld4(&cui[o]);
  float4 r = make_float4((m*(hv.x*cav.x) + im*fev.x)*cv.x,
                         (m*(hv.y*cav.y) + im*fev.y)*cv.y,
                         (m*(hv.z*cav.z) + im*fev.z)*cv.z,
                         (m*(hv.w*cav.w) + im*fev.w)*cv.w);
  st4(&msg[o], r);
}

// out[n] = n<U ? hu[n]*cu[n] : hi[n-U]*ci[n-U]   (row stride 64)
__global__ __launch_bounds__(256) void finish_ud(
    const float* __restrict__ hu, const float* __restrict__ cu,
    const float* __restrict__ hi, const float* __restrict__ ci,
    float* __restrict__ out)
{
  int gid = blockIdx.x*256 + threadIdx.x;
  if (gid >= N_CNT*16) return;
  int n = gid >> 4, q = (gid & 15) << 2;
  float4 v;
  if (n < U_CNT) { size_t o = (size_t)n*64 + q;          v = mul4(ld4(&hu[o]), ld4(&cu[o])); }
  else           { size_t o = (size_t)(n-U_CNT)*64 + q;  v = mul4(ld4(&hi[o]), ld4(&ci[o])); }
  st4(&out[(size_t)n*64 + q], v);
}

// same, but writes column-block kcol of a row-stride-320 output
__global__ __launch_bounds__(256) void finish_5(
    const float* __restrict__ hu, const float* __restrict__ cu,
    const float* __restrict__ hi, const float* __restrict__ ci,
    float* __restrict__ out, int kcol)
{
  int gid = blockIdx.x*256 + threadIdx.x;
  if (gid >= N_CNT*16) return;
  int n = gid >> 4, q = (gid & 15) << 2;
  float4 v;
  if (n < U_CNT) { size_t o = (size_t)n*64 + q;          v = mul4(ld4(&hu[o]), ld4(&cu[o])); }
  else           { size_t o = (size_t)(n-U_CNT)*64 + q;  v = mul4(ld4(&hi[o]), ld4(&ci[o])); }
  st4(&out[(size_t)n*320 + (size_t)kcol*64 + q], v);
}

__global__ __launch_bounds__(256) void zero_kernel(float4* __restrict__ p, int n4)
{
  int gid = blockIdx.x*256 + threadIdx.x;
  if (gid < n4) p[gid] = make_float4(0.f,0.f,0.f,0.f);
}

extern "C" void kernel_launch(void* const* d_in, const int* in_sizes, int n_in,
                              void* d_out, int out_size, void* d_ws, size_t ws_size,
                              hipStream_t stream)
{
  (void)in_sizes; (void)n_in; (void)out_size; (void)ws_size;
  auto F = [&](int i){ return (const float*)d_in[i]; };
  auto Ix = [&](int i){ return (const int*)d_in[i]; };

  // --- inputs in setup_inputs() dict order ---
  const float* feature1 = F(0);
  const float* feature2 = F(1);
  const float* feature3 = F(2);
  const float* weightK[5]   = {F(3),F(4),F(5),F(6),F(7)};
  const float* W_review1 = F(8);
  const float* W_review2 = F(9);
  const float* rating_emb[6] = {F(10),F(11),F(12),F(13),F(14),F(15)};
  const float* W_aspect  = F(16);
  const float* W_aspect2 = F(17);
  const float* W_count_user = F(18);
  const float* b_count_user = F(19);
  const float* W_count_item = F(20);
  const float* b_count_item = F(21);
  const float* aspect_fe  = F(22);
  const float* aspect_cau = F(23);
  const float* aspect_cai = F(24);
  const float* user_cau = F(25);
  const float* user_cui = F(26);
  const float* item_cai = F(27);
  const float* item_ciu = F(28);
  const float* user_cuiK[5] = {F(29),F(31),F(33),F(35),F(37)};
  const float* item_ciuK[5] = {F(30),F(32),F(34),F(36),F(38)};
  const float* user_mask = F(39);
  const float* item_mask = F(40);
  const float* user_aspect_count = F(41);
  const float* item_aspect_count = F(42);
  // 43,44: ui_review/iu_review unused by reference
  const float* uiK_review[5] = {F(45),F(47),F(49),F(51),F(53)};
  const float* iuK_review[5] = {F(46),F(48),F(50),F(52),F(54)};
  const int* au_src = Ix(55); const int* au_dst = Ix(56);
  const int* ai_src = Ix(57); const int* ai_dst = Ix(58);
  const int* ui_src = Ix(59); const int* ui_dst = Ix(60); const int* ui_rating = Ix(61);
  const int* iu_src = Ix(62); const int* iu_dst = Ix(63); const int* iu_rating = Ix(64);
  const int* uiK_src[5] = {Ix(65),Ix(69),Ix(73),Ix(77),Ix(81)};
  const int* uiK_dst[5] = {Ix(66),Ix(70),Ix(74),Ix(78),Ix(82)};
  const int* iuK_src[5] = {Ix(67),Ix(71),Ix(75),Ix(79),Ix(83)};
  const int* iuK_dst[5] = {Ix(68),Ix(72),Ix(76),Ix(80),Ix(84)};

  float* out = (float*)d_out;
  float* out4 = out + 3*(size_t)N_CNT*64;              // (N,320)
  float* out5 = out + 8*(size_t)N_CNT*64;              // (N,320)

  // --- workspace layout ---
  float* ws = (float*)d_ws;
  size_t off = 0;
  auto alloc = [&](size_t n){ float* p = ws + off; off += n; return p; };
  float* msg_au = alloc((size_t)A_CNT*64);
  float* msg_ai = alloc((size_t)A_CNT*64);
  float* zg = ws + off;                                // zero-group (8 bufs)
  float* h_u_a = alloc(UD_N); float* h_i_a = alloc(ID_N);
  float* h_u1  = alloc(UD_N); float* h_i1  = alloc(ID_N);
  float* h_u3  = alloc(UD_N); float* h_i3  = alloc(ID_N);
  float* h_u5  = alloc(UD_N); float* h_i5  = alloc(ID_N);
  size_t zg_n = (size_t)((ws + off) - zg);
  float* zk = ws + off;                                // per-k zero-group (4 bufs)
  float* h_uk = alloc(UD_N); float* h_ik = alloc(ID_N);
  float* h_ur = alloc(UD_N); float* h_ir = alloc(ID_N);
  size_t zk_n = (size_t)((ws + off) - zk);
  float* g_u  = alloc(UD_N); float* g_i = alloc(ID_N);
  float* re_u = alloc((size_t)ER*64);
  float* re_i = alloc((size_t)ER*64);

  const int BS = 256;
  const int gZg   = (int)((zg_n/4 + BS-1)/BS);
  const int gZk   = (int)((zk_n/4 + BS-1)/BS);
  const int gEau  = EAU*16/BS;          // 18750
  const int gEui  = EUI*16/BS;          // 18750
  const int gEr   = ER*16/BS;           // 3750
  const int gU    = (U_CNT*16 + BS-1)/BS;
  const int gI    = (I_CNT*16 + BS-1)/BS;
  const int gN    = (N_CNT*16 + BS-1)/BS;
  const int gGu   = (U_CNT + 63)/64;
  const int gGi   = (I_CNT + 63)/64;
  const int gGr   = (ER + 63)/64;
  const int gGa   = A_CNT/64;

  // zero all accumulator buffers (harness does not re-zero ws between replays)
  zero_kernel<<<gZg, BS, 0, stream>>>((float4*)zg, (int)(zg_n/4));

  // aspect messages: msg_au = (aspect_fe @ W_aspect) * aspect_cau (fused epilogue)
  gemm64<<<gGa, BS, 0, stream>>>(aspect_fe, A_CNT, 64, W_aspect,  nullptr, aspect_cau, msg_au);
  gemm64<<<gGa, BS, 0, stream>>>(aspect_fe, A_CNT, 64, W_aspect2, nullptr, aspect_cai, msg_ai);

  // h_u_a = seg(msg_au[au_src], au_dst, U);  h_i_a likewise
  scatter_plain<<<gEau, BS, 0, stream>>>(msg_au, au_src, au_dst, EAU, h_u_a);
  scatter_plain<<<gEau, BS, 0, stream>>>(msg_ai, ai_src, ai_dst, EAU, h_i_a);

  // from_a_* blend, folded with *user_cui / *item_ciu, in place
  blend_msg<<<gU, BS, 0, stream>>>(h_u_a, user_cau, feature2,                     user_mask, user_cui, h_u_a, U_CNT);
  blend_msg<<<gI, BS, 0, stream>>>(h_i_a, item_cai, feature2 + (size_t)U_CNT*64,  item_mask, item_ciu, h_i_a, I_CNT);

  // senti: h_i1 over ui edges (emb1), h_u1 over iu edges (emb2)
  scatter_sig<<<gEui, BS, 0, stream>>>(h_u_a, nullptr, ui_src, ui_dst, ui_rating, rating_emb[0], EUI, h_i1);
  scatter_sig<<<gEui, BS, 0, stream>>>(h_i_a, nullptr, iu_src, iu_dst, iu_rating, rating_emb[1], EUI, h_u1);

  // count branch: big GEMMs + blend (in place) + scatter
  gemm64<<<gGu, BS, 0, stream>>>(user_aspect_count, U_CNT, NC_K, W_count_user, b_count_user, nullptr, g_u);
  gemm64<<<gGi, BS, 0, stream>>>(item_aspect_count, I_CNT, NC_K, W_count_item, b_count_item, nullptr, g_i);
  blend_msg<<<gU, BS, 0, stream>>>(g_u, user_cau, feature3,                     user_mask, user_cui, g_u, U_CNT);
  blend_msg<<<gI, BS, 0, stream>>>(g_i, item_cai, feature3 + (size_t)U_CNT*64,  item_mask, item_ciu, g_i, I_CNT);
  scatter_sig<<<gEui, BS, 0, stream>>>(g_u, nullptr, ui_src, ui_dst, ui_rating, rating_emb[2], EUI, h_i3);
  scatter_sig<<<gEui, BS, 0, stream>>>(g_i, nullptr, iu_src, iu_dst, iu_rating, rating_emb[3], EUI, h_u3);

  // fe branch: message = feature1 * cui computed inline in the gather
  scatter_sig<<<gEui, BS, 0, stream>>>(feature1,                    user_cui, ui_src, ui_dst, ui_rating, rating_emb[4], EUI, h_i5);
  scatter_sig<<<gEui, BS, 0, stream>>>(feature1 + (size_t)U_CNT*64, item_ciu, iu_src, iu_dst, iu_rating, rating_emb[5], EUI, h_u5);

  // outputs 1-3
  finish_ud<<<gN, BS, 0, stream>>>(h_u1, user_cui, h_i1, item_ciu, out);
  finish_ud<<<gN, BS, 0, stream>>>(h_u3, user_cui, h_i3, item_ciu, out + (size_t)N_CNT*64);
  finish_ud<<<gN, BS, 0, stream>>>(h_u5, user_cui, h_i5, item_ciu, out + 2*(size_t)N_CNT*64);

  // fe5 / re branch (k = 0..4)
  for (int k = 0; k < 5; ++k) {
    gemm64<<<gGr, BS, 0, stream>>>(uiK_review[k], ER, 64, W_review1, nullptr, nullptr, re_u);
    gemm64<<<gGr, BS, 0, stream>>>(iuK_review[k], ER, 64, W_review2, nullptr, nullptr, re_i);
    zero_kernel<<<gZk, BS, 0, stream>>>((float4*)zk, (int)(zk_n/4));
    // ui side: scatter to items (h_ik, h_ir)
    scatter_fe5<<<gEr, BS, 0, stream>>>(re_u, weightK[k],                    user_cuiK[k],
                                        uiK_src[k], uiK_dst[k], ER, h_ik, h_ir);
    // iu side: scatter to users (h_uk, h_ur)
    scatter_fe5<<<gEr, BS, 0, stream>>>(re_i, weightK[k] + (size_t)U_CNT*64, item_ciuK[k],
                                        iuK_src[k], iuK_dst[k], ER, h_uk, h_ur);
    finish_5<<<gN, BS, 0, stream>>>(h_uk, user_cuiK[k], h_ik, item_ciuK[k], out4, k);
    finish_5<<<gN, BS, 0, stream>>>(h_ur, user_cuiK[k], h_ir, item_ciuK[k], out5, k);
  }
}

// Round 2
// 1057.866 us; speedup vs baseline: 3.5039x; 3.5039x over previous
//
#include <hip/hip_runtime.h>
#include <cstddef>

#define U_CNT 20000
#define I_CNT 15000
#define N_CNT 35000
#define A_CNT 2048
#define NC_K  2048
#define EAU   300000
#define EUI   300000
#define ER    60000
#define NLIST 14

__device__ __forceinline__ float4 ld4(const float* p){ return *reinterpret_cast<const float4*>(p); }
__device__ __forceinline__ void st4(float* p, float4 v){ *reinterpret_cast<float4*>(p) = v; }
__device__ __forceinline__ float4 mul4(float4 a, float4 b){ return make_float4(a.x*b.x, a.y*b.y, a.z*b.z, a.w*b.w); }
__device__ __forceinline__ float4 add4(float4 a, float4 b){ return make_float4(a.x+b.x, a.y+b.y, a.z+b.z, a.w+b.w); }
__device__ __forceinline__ float4 fmas4(float s, float4 b, float4 c){
  return make_float4(fmaf(s,b.x,c.x), fmaf(s,b.y,c.y), fmaf(s,b.z,c.z), fmaf(s,b.w,c.w));
}

// ---------------- batched CSR build ----------------
struct HistMeta { const int* dst[NLIST]; int* cnt[NLIST]; int E[NLIST]; };
struct ScanMeta { int* cnt[NLIST]; int* offs[NLIST]; int* cur[NLIST]; int nseg[NLIST]; };
struct FillMeta { const int* dst[NLIST]; int* cur[NLIST]; int* perm[NLIST]; int E[NLIST]; };

__global__ __launch_bounds__(256) void zero_kernel(float4* __restrict__ p, int n4)
{
  int gid = blockIdx.x*256 + threadIdx.x;
  if (gid < n4) p[gid] = make_float4(0.f,0.f,0.f,0.f);
}

__global__ __launch_bounds__(256) void hist_batched(HistMeta m)
{
  int li = blockIdx.y;
  int i = blockIdx.x*256 + threadIdx.x;
  if (i < m.E[li]) atomicAdd(&m.cnt[li][m.dst[li][i]], 1);
}

__global__ __launch_bounds__(256) void scan_batched(ScanMeta m)
{
  int li = blockIdx.x;
  int n = m.nseg[li];
  int* cnt = m.cnt[li]; int* offs = m.offs[li]; int* cur = m.cur[li];
  __shared__ int buf[256];
  int tid = threadIdx.x;
  int carry = 0;
  for (int base = 0; base < n; base += 256) {
    int i = base + tid;
    int v = (i < n) ? cnt[i] : 0;
    buf[tid] = v;
    __syncthreads();
    for (int off = 1; off < 256; off <<= 1) {
      int t = (tid >= off) ? buf[tid-off] : 0;
      __syncthreads();
      buf[tid] += t;
      __syncthreads();
    }
    if (i < n) { int e = carry + buf[tid] - v; offs[i] = e; cur[i] = e; }
    carry += buf[255];
    __syncthreads();
  }
  if (tid == 0) offs[n] = carry;
}

__global__ __launch_bounds__(256) void fill_batched(FillMeta m)
{
  int li = blockIdx.y;
  int i = blockIdx.x*256 + threadIdx.x;
  if (i < m.E[li]) {
    int d = m.dst[li][i];
    int p = atomicAdd(&m.cur[li][d], 1);
    m.perm[li][p] = i;
  }
}

// ---------------- small precompute ----------------
// sigt[k][r][j] = sigmoid(emb_k[r][j]), k=0..5, tables of 320 floats each
__global__ __launch_bounds__(256) void sigtab_kernel(
    const float* __restrict__ e0, const float* __restrict__ e1,
    const float* __restrict__ e2, const float* __restrict__ e3,
    const float* __restrict__ e4, const float* __restrict__ e5,
    float* __restrict__ out)
{
  int i = blockIdx.x*256 + threadIdx.x;
  if (i >= 6*320) return;
  int k = i / 320, j = i % 320;
  const float* e = (k==0)?e0:(k==1)?e1:(k==2)?e2:(k==3)?e3:(k==4)?e4:e5;
  out[i] = 1.f/(1.f + __expf(-e[j]));
}

// fe1c[n] = feature1[n] * (n<U ? user_cui[n] : item_ciu[n-U])
__global__ __launch_bounds__(256) void fe1c_kernel(
    const float* __restrict__ f1, const float* __restrict__ cui,
    const float* __restrict__ ciu, float* __restrict__ out)
{
  int gid = blockIdx.x*256 + threadIdx.x;
  if (gid >= N_CNT*16) return;
  int n = gid >> 4, q = (gid & 15) << 2;
  size_t o = (size_t)n*64 + q;
  float4 v = ld4(&f1[o]);
  float4 c = (n < U_CNT) ? ld4(&cui[o]) : ld4(&ciu[(size_t)(n-U_CNT)*64 + q]);
  st4(&out[o], mul4(v, c));
}

// ---------------------------------------------------------------------------
// C[M,64] = A[M,K] @ W[K,64] (+ bias) then epilogue:
//   if mask:  C = (mask*(C*ca) + (1-mask)*fe) * cui
//   elif mulp: C = C * mulp
// ---------------------------------------------------------------------------
__global__ __launch_bounds__(256) void gemm64(
    const float* __restrict__ A, int M, int K,
    const float* __restrict__ W, const float* __restrict__ bias,
    const float* __restrict__ mulp,
    const float* __restrict__ mask, const float* __restrict__ ca,
    const float* __restrict__ fe, const float* __restrict__ cui,
    float* __restrict__ C)
{
  __shared__ float As[64][36];
  __shared__ float Ws[32][64];
  const int t  = threadIdx.x;
  const int r0 = blockIdx.x * 64;
  const int ty = t >> 4, tx = t & 15;
  float4 acc0 = make_float4(0,0,0,0), acc1 = acc0, acc2 = acc0, acc3 = acc0;

  for (int k0 = 0; k0 < K; k0 += 32) {
    __syncthreads();
    #pragma unroll
    for (int i = 0; i < 2; ++i) {
      int f = t + i*256;
      int row = f >> 3, caa = (f & 7) << 2;
      float4 v = make_float4(0.f,0.f,0.f,0.f);
      int r = r0 + row;
      if (r < M) v = ld4(&A[(size_t)r*K + k0 + caa]);
      st4(&As[row][caa], v);
      int kk = f >> 4, cb = (f & 15) << 2;
      st4(&Ws[kk][cb], ld4(&W[(size_t)(k0+kk)*64 + cb]));
    }
    __syncthreads();
    #pragma unroll
    for (int kk = 0; kk < 32; kk += 4) {
      float4 a0 = ld4(&As[ty*4+0][kk]);
      float4 a1 = ld4(&As[ty*4+1][kk]);
      float4 a2 = ld4(&As[ty*4+2][kk]);
      float4 a3 = ld4(&As[ty*4+3][kk]);
      float a0v[4] = {a0.x,a0.y,a0.z,a0.w};
      float a1v[4] = {a1.x,a1.y,a1.z,a1.w};
      float a2v[4] = {a2.x,a2.y,a2.z,a2.w};
      float a3v[4] = {a3.x,a3.y,a3.z,a3.w};
      #pragma unroll
      for (int j = 0; j < 4; ++j) {
        float4 wv = ld4(&Ws[kk+j][tx<<2]);
        acc0 = fmas4(a0v[j], wv, acc0);
        acc1 = fmas4(a1v[j], wv, acc1);
        acc2 = fmas4(a2v[j], wv, acc2);
        acc3 = fmas4(a3v[j], wv, acc3);
      }
    }
  }

  float4 bv = make_float4(0,0,0,0);
  if (bias) bv = ld4(&bias[tx<<2]);
  float4 accs[4] = {acc0,acc1,acc2,acc3};
  #pragma unroll
  for (int i = 0; i < 4; ++i) {
    int r = r0 + ty*4 + i;
    if (r < M) {
      float4 v = add4(accs[i], bv);
      size_t o = (size_t)r*64 + (tx<<2);
      if (mask) {
        float mm = mask[r], im = 1.f - mm;
        float4 cav = ld4(&ca[o]), fev = ld4(&fe[o]), cv = ld4(&cui[o]);
        v = make_float4((mm*(v.x*cav.x) + im*fev.x)*cv.x,
                        (mm*(v.y*cav.y) + im*fev.y)*cv.y,
                        (mm*(v.z*cav.z) + im*fev.z)*cv.z,
                        (mm*(v.w*cav.w) + im*fev.w)*cv.w);
      } else if (mulp) {
        v = mul4(v, ld4(&mulp[o]));
      }
      st4(&C[o], v);
    }
  }
}

// ---------------- CSR gathers (no atomics) ----------------
// 16 lanes per dst row, float4 per lane; 16 rows per 256-thread block.

// outb[d] = (mask[d]*(sum*ca[d]) + (1-mask[d])*fe[d]) * cui[d]
__global__ __launch_bounds__(256) void gather_blend(
    const int* __restrict__ offs, const int* __restrict__ perm,
    const int* __restrict__ src, const float* __restrict__ msg,
    const float* __restrict__ mask, const float* __restrict__ ca,
    const float* __restrict__ fe, const float* __restrict__ cui,
    float* __restrict__ outb, int nseg)
{
  int tid = threadIdx.x;
  int d = blockIdx.x*16 + (tid >> 4);
  if (d >= nseg) return;
  int q = (tid & 15) << 2;
  float4 a = make_float4(0,0,0,0);
  int j1 = offs[d+1];
  for (int j = offs[d]; j < j1; ++j) {
    int s = src[perm[j]];
    a = add4(a, ld4(&msg[(size_t)s*64 + q]));
  }
  size_t o = (size_t)d*64 + q;
  float m = mask[d], im = 1.f - m;
  float4 cav = ld4(&ca[o]), fev = ld4(&fe[o]), cv = ld4(&cui[o]);
  st4(&outb[o], make_float4((m*(a.x*cav.x) + im*fev.x)*cv.x,
                            (m*(a.y*cav.y) + im*fev.y)*cv.y,
                            (m*(a.z*cav.z) + im*fev.z)*cv.z,
                            (m*(a.w*cav.w) + im*fev.w)*cv.w));
}

// three fused segment-sums over one edge list; outX[d] = accX * cmul[d]
__global__ __launch_bounds__(256) void gather3(
    const int* __restrict__ offs, const int* __restrict__ perm,
    const int* __restrict__ src, const int* __restrict__ rating,
    const float* __restrict__ msgA, const float* __restrict__ msgB,
    const float* __restrict__ msgC,
    const float* __restrict__ sigA, const float* __restrict__ sigB,
    const float* __restrict__ sigC,
    const float* __restrict__ cmul,
    float* __restrict__ outA, float* __restrict__ outB, float* __restrict__ outC,
    int nseg)
{
  int tid = threadIdx.x;
  int d = blockIdx.x*16 + (tid >> 4);
  if (d >= nseg) return;
  int q = (tid & 15) << 2;
  float4 a0 = make_float4(0,0,0,0), a1 = a0, a2 = a0;
  int j1 = offs[d+1];
  for (int j = offs[d]; j < j1; ++j) {
    int e = perm[j];
    int s = src[e];
    int r = rating[e];
    size_t so = (size_t)s*64 + q;
    int ro = r*64 + q;
    a0 = add4(a0, mul4(ld4(&msgA[so]), ld4(&sigA[ro])));
    a1 = add4(a1, mul4(ld4(&msgB[so]), ld4(&sigB[ro])));
    a2 = add4(a2, mul4(ld4(&msgC[so]), ld4(&sigC[ro])));
  }
  size_t o = (size_t)d*64 + q;
  float4 c = ld4(&cmul[o]);
  st4(&outA[o], mul4(a0, c));
  st4(&outB[o], mul4(a1, c));
  st4(&outC[o], mul4(a2, c));
}

// fe5/re pair: accA += (w[s]+re[e])*cuiS[s]; accB += re[e]*cuiS[s]
// outA[d*320+q] = accA*cmulD[d];  outB likewise (row stride 320)
__global__ __launch_bounds__(256) void gather_fe5(
    const int* __restrict__ offs, const int* __restrict__ perm,
    const int* __restrict__ src, const float* __restrict__ re,
    const float* __restrict__ w, const float* __restrict__ cuiS,
    const float* __restrict__ cmulD,
    float* __restrict__ outA, float* __restrict__ outB, int nseg)
{
  int tid = threadIdx.x;
  int d = blockIdx.x*16 + (tid >> 4);
  if (d >= nseg) return;
  int q = (tid & 15) << 2;
  float4 a0 = make_float4(0,0,0,0), a1 = a0;
  int j1 = offs[d+1];
  for (int j = offs[d]; j < j1; ++j) {
    int e = perm[j];
    int s = src[e];
    float4 rv = ld4(&re[(size_t)e*64 + q]);
    float4 cv = ld4(&cuiS[(size_t)s*64 + q]);
    float4 wv = ld4(&w[(size_t)s*64 + q]);
    a0 = add4(a0, mul4(add4(wv, rv), cv));
    a1 = add4(a1, mul4(rv, cv));
  }
  float4 c = ld4(&cmulD[(size_t)d*64 + q]);
  size_t o = (size_t)d*320 + q;
  st4(&outA[o], mul4(a0, c));
  st4(&outB[o], mul4(a1, c));
}

extern "C" void kernel_launch(void* const* d_in, const int* in_sizes, int n_in,
                              void* d_out, int out_size, void* d_ws, size_t ws_size,
                              hipStream_t stream)
{
  (void)in_sizes; (void)n_in; (void)out_size; (void)ws_size;
  auto F = [&](int i){ return (const float*)d_in[i]; };
  auto Ix = [&](int i){ return (const int*)d_in[i]; };

  const float* feature1 = F(0);
  const float* feature2 = F(1);
  const float* feature3 = F(2);
  const float* weightK[5]   = {F(3),F(4),F(5),F(6),F(7)};
  const float* W_review1 = F(8);
  const float* W_review2 = F(9);
  const float* rating_emb[6] = {F(10),F(11),F(12),F(13),F(14),F(15)};
  const float* W_aspect  = F(16);
  const float* W_aspect2 = F(17);
  const float* W_count_user = F(18);
  const float* b_count_user = F(19);
  const float* W_count_item = F(20);
  const float* b_count_item = F(21);
  const float* aspect_fe  = F(22);
  const float* aspect_cau = F(23);
  const float* aspect_cai = F(24);
  const float* user_cau = F(25);
  const float* user_cui = F(26);
  const float* item_cai = F(27);
  const float* item_ciu = F(28);
  const float* user_cuiK[5] = {F(29),F(31),F(33),F(35),F(37)};
  const float* item_ciuK[5] = {F(30),F(32),F(34),F(36),F(38)};
  const float* user_mask = F(39);
  const float* item_mask = F(40);
  const float* user_aspect_count = F(41);
  const float* item_aspect_count = F(42);
  const float* uiK_review[5] = {F(45),F(47),F(49),F(51),F(53)};
  const float* iuK_review[5] = {F(46),F(48),F(50),F(52),F(54)};
  const int* au_src = Ix(55); const int* au_dst = Ix(56);
  const int* ai_src = Ix(57); const int* ai_dst = Ix(58);
  const int* ui_src = Ix(59); const int* ui_dst = Ix(60); const int* ui_rating = Ix(61);
  const int* iu_src = Ix(62); const int* iu_dst = Ix(63); const int* iu_rating = Ix(64);
  const int* uiK_src[5] = {Ix(65),Ix(69),Ix(73),Ix(77),Ix(81)};
  const int* uiK_dst[5] = {Ix(66),Ix(70),Ix(74),Ix(78),Ix(82)};
  const int* iuK_src[5] = {Ix(67),Ix(71),Ix(75),Ix(79),Ix(83)};
  const int* iuK_dst[5] = {Ix(68),Ix(72),Ix(76),Ix(80),Ix(84)};

  float* out  = (float*)d_out;
  float* out2 = out + (size_t)N_CNT*64;
  float* out3 = out + 2*(size_t)N_CNT*64;
  float* out4 = out + 3*(size_t)N_CNT*64;              // (N,320)
  float* out5 = out + 8*(size_t)N_CNT*64;              // (N,320)

  // --- workspace ---
  float* ws = (float*)d_ws;
  size_t off = 0;
  auto alloc = [&](size_t n){ float* p = ws + off; off += n; return p; };
  float* sigt   = alloc(6*320);
  float* msg_au = alloc((size_t)A_CNT*64);
  float* msg_ai = alloc((size_t)A_CNT*64);
  float* h_u_a  = alloc((size_t)U_CNT*64);
  float* h_i_a  = alloc((size_t)I_CNT*64);
  float* g_u    = alloc((size_t)U_CNT*64);
  float* g_i    = alloc((size_t)I_CNT*64);
  float* fe1c   = alloc((size_t)N_CNT*64);
  float* re_u   = alloc((size_t)ER*64);
  float* re_i   = alloc((size_t)ER*64);
  off = (off + 3) & ~(size_t)3;                        // 16B align int region
  int* ibase = (int*)(ws + off);

  // CSR lists: 0=au(U) 1=ai(I) 2=ui(I) 3=iu(U) 4..8=uiK(I) 9..13=iuK(U)
  const int* l_dst[NLIST] = {au_dst, ai_dst, ui_dst, iu_dst,
                             uiK_dst[0],uiK_dst[1],uiK_dst[2],uiK_dst[3],uiK_dst[4],
                             iuK_dst[0],iuK_dst[1],iuK_dst[2],iuK_dst[3],iuK_dst[4]};
  int l_E[NLIST]    = {EAU,EAU,EUI,EUI, ER,ER,ER,ER,ER, ER,ER,ER,ER,ER};
  int l_nseg[NLIST] = {U_CNT,I_CNT,I_CNT,U_CNT, I_CNT,I_CNT,I_CNT,I_CNT,I_CNT,
                       U_CNT,U_CNT,U_CNT,U_CNT,U_CNT};
  int* l_cnt[NLIST]; int* l_offs[NLIST]; int* l_cur[NLIST]; int* l_perm[NLIST];
  size_t ioff = 0;
  for (int l = 0; l < NLIST; ++l) {
    l_cnt[l]  = ibase + ioff; ioff += l_nseg[l];
    l_offs[l] = ibase + ioff; ioff += l_nseg[l] + 1;
    l_cur[l]  = ibase + ioff; ioff += l_nseg[l];
    l_perm[l] = ibase + ioff; ioff += l_E[l];
  }
  size_t int_n = (ioff + 3) & ~(size_t)3;

  HistMeta hm; ScanMeta sm; FillMeta fm;
  for (int l = 0; l < NLIST; ++l) {
    hm.dst[l]=l_dst[l]; hm.cnt[l]=l_cnt[l]; hm.E[l]=l_E[l];
    sm.cnt[l]=l_cnt[l]; sm.offs[l]=l_offs[l]; sm.cur[l]=l_cur[l]; sm.nseg[l]=l_nseg[l];
    fm.dst[l]=l_dst[l]; fm.cur[l]=l_cur[l]; fm.perm[l]=l_perm[l]; fm.E[l]=l_E[l];
  }

  const int BS = 256;
  const int gE   = (EAU + BS-1)/BS;          // covers max E
  const int gU16 = (U_CNT + 15)/16;
  const int gI16 = (I_CNT + 15)/16;
  const int gN16 = (N_CNT*16 + BS-1)/BS;
  const int gGu  = (U_CNT + 63)/64;
  const int gGi  = (I_CNT + 63)/64;
  const int gGr  = (ER + 63)/64;
  const int gGa  = A_CNT/64;

  // CSR build
  zero_kernel<<<(int)((int_n/4 + BS-1)/BS), BS, 0, stream>>>((float4*)ibase, (int)(int_n/4));
  hist_batched<<<dim3(gE, NLIST), BS, 0, stream>>>(hm);
  scan_batched<<<NLIST, BS, 0, stream>>>(sm);
  fill_batched<<<dim3(gE, NLIST), BS, 0, stream>>>(fm);

  // small precompute
  sigtab_kernel<<<8, BS, 0, stream>>>(rating_emb[0],rating_emb[1],rating_emb[2],
                                      rating_emb[3],rating_emb[4],rating_emb[5], sigt);
  fe1c_kernel<<<gN16, BS, 0, stream>>>(feature1, user_cui, item_ciu, fe1c);

  // aspect messages (epilogue * aspect_cau / cai)
  gemm64<<<gGa, BS, 0, stream>>>(aspect_fe, A_CNT, 64, W_aspect,  nullptr, aspect_cau,
                                 nullptr,nullptr,nullptr,nullptr, msg_au);
  gemm64<<<gGa, BS, 0, stream>>>(aspect_fe, A_CNT, 64, W_aspect2, nullptr, aspect_cai,
                                 nullptr,nullptr,nullptr,nullptr, msg_ai);

  // h_u_a = blend(seg(msg_au)) * user_cui   (ready message for ui edges)
  gather_blend<<<gU16, BS, 0, stream>>>(l_offs[0], l_perm[0], au_src, msg_au,
      user_mask, user_cau, feature2, user_cui, h_u_a, U_CNT);
  gather_blend<<<gI16, BS, 0, stream>>>(l_offs[1], l_perm[1], ai_src, msg_ai,
      item_mask, item_cai, feature2 + (size_t)U_CNT*64, item_ciu, h_i_a, I_CNT);

  // count branch GEMMs with fused bias+blend+*cui epilogue
  gemm64<<<gGu, BS, 0, stream>>>(user_aspect_count, U_CNT, NC_K, W_count_user, b_count_user,
      nullptr, user_mask, user_cau, feature3, user_cui, g_u);
  gemm64<<<gGi, BS, 0, stream>>>(item_aspect_count, I_CNT, NC_K, W_count_item, b_count_item,
      nullptr, item_mask, item_cai, feature3 + (size_t)U_CNT*64, item_ciu, g_i);

  // fused 3-acc gathers -> outputs 1..3 directly
  gather3<<<gI16, BS, 0, stream>>>(l_offs[2], l_perm[2], ui_src, ui_rating,
      h_u_a, g_u, fe1c, sigt + 0*320, sigt + 2*320, sigt + 4*320,
      item_ciu, out + (size_t)U_CNT*64, out2 + (size_t)U_CNT*64, out3 + (size_t)U_CNT*64, I_CNT);
  gather3<<<gU16, BS, 0, stream>>>(l_offs[3], l_perm[3], iu_src, iu_rating,
      h_i_a, g_i, fe1c + (size_t)U_CNT*64, sigt + 1*320, sigt + 3*320, sigt + 5*320,
      user_cui, out, out2, out3, U_CNT);

  // fe5 / re branch
  for (int k = 0; k < 5; ++k) {
    gemm64<<<gGr, BS, 0, stream>>>(uiK_review[k], ER, 64, W_review1, nullptr, nullptr,
                                   nullptr,nullptr,nullptr,nullptr, re_u);
    gemm64<<<gGr, BS, 0, stream>>>(iuK_review[k], ER, 64, W_review2, nullptr, nullptr,
                                   nullptr,nullptr,nullptr,nullptr, re_i);
    // ui_k: dst=items -> rows U..N of out4/out5, col k
    gather_fe5<<<gI16, BS, 0, stream>>>(l_offs[4+k], l_perm[4+k], uiK_src[k], re_u,
        weightK[k], user_cuiK[k], item_ciuK[k],
        out4 + (size_t)U_CNT*320 + (size_t)k*64, out5 + (size_t)U_CNT*320 + (size_t)k*64, I_CNT);
    // iu_k: dst=users -> rows 0..U of out4/out5, col k
    gather_fe5<<<gU16, BS, 0, stream>>>(l_offs[9+k], l_perm[9+k], iuK_src[k], re_i,
        weightK[k] + (size_t)U_CNT*64, item_ciuK[k], user_cuiK[k],
        out4 + (size_t)k*64, out5 + (size_t)k*64, U_CNT);
  }
}

// Round 3
// 684.515 us; speedup vs baseline: 5.4151x; 1.5454x over previous
//
#include <hip/hip_runtime.h>
#include <cstddef>

#define U_CNT 20000
#define I_CNT 15000
#define N_CNT 35000
#define A_CNT 2048
#define NC_K  2048
#define EAU   300000
#define EUI   300000
#define ER    60000
#define NLIST 14

__device__ __forceinline__ float4 ld4(const float* p){ return *reinterpret_cast<const float4*>(p); }
__device__ __forceinline__ void st4(float* p, float4 v){ *reinterpret_cast<float4*>(p) = v; }
__device__ __forceinline__ float4 mul4(float4 a, float4 b){ return make_float4(a.x*b.x, a.y*b.y, a.z*b.z, a.w*b.w); }
__device__ __forceinline__ float4 add4(float4 a, float4 b){ return make_float4(a.x+b.x, a.y+b.y, a.z+b.z, a.w+b.w); }
__device__ __forceinline__ float4 fmas4(float s, float4 b, float4 c){
  return make_float4(fmaf(s,b.x,c.x), fmaf(s,b.y,c.y), fmaf(s,b.z,c.z), fmaf(s,b.w,c.w));
}

// ---------------- CSR build (batched over 14 lists) ----------------
struct CsrMeta {
  const int* dst[NLIST];
  int* cnt[NLIST]; int* offs[NLIST]; int* cur[NLIST]; int* perm[NLIST];
  int E[NLIST]; int nseg[NLIST];
};

__global__ __launch_bounds__(256) void zero_kernel(float4* __restrict__ p, int n4)
{
  int gid = blockIdx.x*256 + threadIdx.x;
  if (gid < n4) p[gid] = make_float4(0.f,0.f,0.f,0.f);
}

__global__ __launch_bounds__(256) void hist_batched(CsrMeta m)
{
  int li = blockIdx.y;
  int i = blockIdx.x*256 + threadIdx.x;
  if (i < m.E[li]) atomicAdd(&m.cnt[li][m.dst[li][i]], 1);
}

// phase 1: per-1024-chunk exclusive scan into offs, chunk totals into bsum[li*32+chunk]
__global__ __launch_bounds__(256) void scan_local(CsrMeta m, int* __restrict__ bsum)
{
  int li = blockIdx.y;
  int n = m.nseg[li];
  const int* cnt = m.cnt[li];
  int* offs = m.offs[li];
  __shared__ int sb[256];
  int tid = threadIdx.x;
  int base = blockIdx.x*1024 + tid*4;
  int v0 = (base+0 < n) ? cnt[base+0] : 0;
  int v1 = (base+1 < n) ? cnt[base+1] : 0;
  int v2 = (base+2 < n) ? cnt[base+2] : 0;
  int v3 = (base+3 < n) ? cnt[base+3] : 0;
  int s = v0+v1+v2+v3;
  sb[tid] = s;
  __syncthreads();
  for (int o = 1; o < 256; o <<= 1) {
    int t = (tid >= o) ? sb[tid-o] : 0;
    __syncthreads();
    sb[tid] += t;
    __syncthreads();
  }
  int e = sb[tid] - s;  // exclusive prefix of this thread within chunk
  if (base+0 < n) offs[base+0] = e;
  if (base+1 < n) offs[base+1] = e + v0;
  if (base+2 < n) offs[base+2] = e + v0 + v1;
  if (base+3 < n) offs[base+3] = e + v0 + v1 + v2;
  if (tid == 0) bsum[li*32 + blockIdx.x] = sb[255];
}

// phase 2: exclusive scan of chunk totals (tiny); also writes offs[n] = grand total
__global__ __launch_bounds__(64) void scan_bsum(CsrMeta m, int* __restrict__ bsum)
{
  int li = blockIdx.x;
  if (threadIdx.x == 0) {
    int n = m.nseg[li];
    int nch = (n + 1023) >> 10;
    int acc = 0;
    for (int c = 0; c < nch; ++c) { int t = bsum[li*32+c]; bsum[li*32+c] = acc; acc += t; }
    m.offs[li][n] = acc;
  }
}

// phase 3: add chunk bases; mirror into cur
__global__ __launch_bounds__(256) void scan_add(CsrMeta m, const int* __restrict__ bsum)
{
  int li = blockIdx.y;
  int i = blockIdx.x*256 + threadIdx.x;
  if (i < m.nseg[li]) {
    int v = m.offs[li][i] + bsum[li*32 + (i >> 10)];
    m.offs[li][i] = v;
    m.cur[li][i] = v;
  }
}

__global__ __launch_bounds__(256) void fill_batched(CsrMeta m)
{
  int li = blockIdx.y;
  int i = blockIdx.x*256 + threadIdx.x;
  if (i < m.E[li]) {
    int d = m.dst[li][i];
    int p = atomicAdd(&m.cur[li][d], 1);
    m.perm[li][p] = i;
  }
}

// ---------------- small precompute ----------------
__global__ __launch_bounds__(256) void sigtab_kernel(
    const float* __restrict__ e0, const float* __restrict__ e1,
    const float* __restrict__ e2, const float* __restrict__ e3,
    const float* __restrict__ e4, const float* __restrict__ e5,
    float* __restrict__ out)
{
  int i = blockIdx.x*256 + threadIdx.x;
  if (i >= 6*320) return;
  int k = i / 320, j = i % 320;
  const float* e = (k==0)?e0:(k==1)?e1:(k==2)?e2:(k==3)?e3:(k==4)?e4:e5;
  out[i] = 1.f/(1.f + __expf(-e[j]));
}

__global__ __launch_bounds__(256) void fe1c_kernel(
    const float* __restrict__ f1, const float* __restrict__ cui,
    const float* __restrict__ ciu, float* __restrict__ out)
{
  int gid = blockIdx.x*256 + threadIdx.x;
  if (gid >= N_CNT*16) return;
  int n = gid >> 4, q = (gid & 15) << 2;
  size_t o = (size_t)n*64 + q;
  float4 v = ld4(&f1[o]);
  float4 c = (n < U_CNT) ? ld4(&cui[o]) : ld4(&ciu[(size_t)(n-U_CNT)*64 + q]);
  st4(&out[o], mul4(v, c));
}

// ---------------------------------------------------------------------------
// Batched K=64 GEMM: C[z] = A[z](M[z],64) @ W[z](64,64) (* mulp[z]) — z = blockIdx.y
// ---------------------------------------------------------------------------
#define K64Z 12
struct K64Meta { const float* A[K64Z]; const float* W[K64Z]; const float* mulp[K64Z];
                 float* C[K64Z]; int M[K64Z]; };

__global__ __launch_bounds__(256) void gemm_k64(K64Meta m)
{
  int z = blockIdx.y;
  int M = m.M[z];
  int r0 = blockIdx.x * 64;
  if (r0 >= M) return;
  const float* __restrict__ A = m.A[z];
  const float* __restrict__ W = m.W[z];
  __shared__ float As[64][36];
  __shared__ float Ws[32][64];
  const int t  = threadIdx.x;
  const int ty = t >> 4, tx = t & 15;
  float4 acc0 = make_float4(0,0,0,0), acc1 = acc0, acc2 = acc0, acc3 = acc0;

  for (int k0 = 0; k0 < 64; k0 += 32) {
    __syncthreads();
    #pragma unroll
    for (int i = 0; i < 2; ++i) {
      int f = t + i*256;
      int row = f >> 3, caa = (f & 7) << 2;
      float4 v = make_float4(0.f,0.f,0.f,0.f);
      int r = r0 + row;
      if (r < M) v = ld4(&A[(size_t)r*64 + k0 + caa]);
      st4(&As[row][caa], v);
      int kk = f >> 4, cb = (f & 15) << 2;
      st4(&Ws[kk][cb], ld4(&W[(size_t)(k0+kk)*64 + cb]));
    }
    __syncthreads();
    #pragma unroll
    for (int kk = 0; kk < 32; kk += 4) {
      float4 a0 = ld4(&As[ty*4+0][kk]);
      float4 a1 = ld4(&As[ty*4+1][kk]);
      float4 a2 = ld4(&As[ty*4+2][kk]);
      float4 a3 = ld4(&As[ty*4+3][kk]);
      float a0v[4] = {a0.x,a0.y,a0.z,a0.w};
      float a1v[4] = {a1.x,a1.y,a1.z,a1.w};
      float a2v[4] = {a2.x,a2.y,a2.z,a2.w};
      float a3v[4] = {a3.x,a3.y,a3.z,a3.w};
      #pragma unroll
      for (int j = 0; j < 4; ++j) {
        float4 wv = ld4(&Ws[kk+j][tx<<2]);
        acc0 = fmas4(a0v[j], wv, acc0);
        acc1 = fmas4(a1v[j], wv, acc1);
        acc2 = fmas4(a2v[j], wv, acc2);
        acc3 = fmas4(a3v[j], wv, acc3);
      }
    }
  }

  const float* mulp = m.mulp[z];
  float* C = m.C[z];
  float4 accs[4] = {acc0,acc1,acc2,acc3};
  #pragma unroll
  for (int i = 0; i < 4; ++i) {
    int r = r0 + ty*4 + i;
    if (r < M) {
      float4 v = accs[i];
      size_t o = (size_t)r*64 + (tx<<2);
      if (mulp) v = mul4(v, ld4(&mulp[o]));
      st4(&C[o], v);
    }
  }
}

// ---------------------------------------------------------------------------
// Split-K GEMM for K=2048: part[sp][r][c] = A[r, sp*chunk : (sp+1)*chunk] @ W-chunk
// grid = (ceil(M/64), nsplit)
// ---------------------------------------------------------------------------
__global__ __launch_bounds__(256) void gemm_splitk(
    const float* __restrict__ A, int M,
    const float* __restrict__ W, float* __restrict__ part)
{
  const int nsplit = gridDim.y;
  const int sp = blockIdx.y;
  const int kchunk = NC_K / nsplit;
  const int k0base = sp * kchunk;
  __shared__ float As[64][36];
  __shared__ float Ws[32][64];
  const int t  = threadIdx.x;
  const int r0 = blockIdx.x * 64;
  const int ty = t >> 4, tx = t & 15;
  float4 acc0 = make_float4(0,0,0,0), acc1 = acc0, acc2 = acc0, acc3 = acc0;

  for (int k0 = k0base; k0 < k0base + kchunk; k0 += 32) {
    __syncthreads();
    #pragma unroll
    for (int i = 0; i < 2; ++i) {
      int f = t + i*256;
      int row = f >> 3, caa = (f & 7) << 2;
      float4 v = make_float4(0.f,0.f,0.f,0.f);
      int r = r0 + row;
      if (r < M) v = ld4(&A[(size_t)r*NC_K + k0 + caa]);
      st4(&As[row][caa], v);
      int kk = f >> 4, cb = (f & 15) << 2;
      st4(&Ws[kk][cb], ld4(&W[(size_t)(k0+kk)*64 + cb]));
    }
    __syncthreads();
    #pragma unroll
    for (int kk = 0; kk < 32; kk += 4) {
      float4 a0 = ld4(&As[ty*4+0][kk]);
      float4 a1 = ld4(&As[ty*4+1][kk]);
      float4 a2 = ld4(&As[ty*4+2][kk]);
      float4 a3 = ld4(&As[ty*4+3][kk]);
      float a0v[4] = {a0.x,a0.y,a0.z,a0.w};
      float a1v[4] = {a1.x,a1.y,a1.z,a1.w};
      float a2v[4] = {a2.x,a2.y,a2.z,a2.w};
      float a3v[4] = {a3.x,a3.y,a3.z,a3.w};
      #pragma unroll
      for (int j = 0; j < 4; ++j) {
        float4 wv = ld4(&Ws[kk+j][tx<<2]);
        acc0 = fmas4(a0v[j], wv, acc0);
        acc1 = fmas4(a1v[j], wv, acc1);
        acc2 = fmas4(a2v[j], wv, acc2);
        acc3 = fmas4(a3v[j], wv, acc3);
      }
    }
  }

  float4 accs[4] = {acc0,acc1,acc2,acc3};
  float* base = part + (size_t)sp * M * 64;
  #pragma unroll
  for (int i = 0; i < 4; ++i) {
    int r = r0 + ty*4 + i;
    if (r < M) st4(&base[(size_t)r*64 + (tx<<2)], accs[i]);
  }
}

// reduce splits + bias + blend epilogue: out = (mask*((sum)*ca) + (1-mask)*fe) * cui
__global__ __launch_bounds__(256) void reduce_blend(
    const float* __restrict__ part, int M, int nsplit,
    const float* __restrict__ bias, const float* __restrict__ mask,
    const float* __restrict__ ca, const float* __restrict__ fe,
    const float* __restrict__ cui, float* __restrict__ outb)
{
  int gid = blockIdx.x*256 + threadIdx.x;
  if (gid >= M*16) return;
  int n = gid >> 4, q = (gid & 15) << 2;
  float4 a = ld4(&bias[q]);
  for (int s = 0; s < nsplit; ++s)
    a = add4(a, ld4(&part[((size_t)s*M + n)*64 + q]));
  size_t o = (size_t)n*64 + q;
  float m = mask[n], im = 1.f - m;
  float4 cav = ld4(&ca[o]), fev = ld4(&fe[o]), cv = ld4(&cui[o]);
  st4(&outb[o], make_float4((m*(a.x*cav.x) + im*fev.x)*cv.x,
                            (m*(a.y*cav.y) + im*fev.y)*cv.y,
                            (m*(a.z*cav.z) + im*fev.z)*cv.z,
                            (m*(a.w*cav.w) + im*fev.w)*cv.w));
}

// ---------------- CSR gathers ----------------
__global__ __launch_bounds__(256) void gather_blend(
    const int* __restrict__ offs, const int* __restrict__ perm,
    const int* __restrict__ src, const float* __restrict__ msg,
    const float* __restrict__ mask, const float* __restrict__ ca,
    const float* __restrict__ fe, const float* __restrict__ cui,
    float* __restrict__ outb, int nseg)
{
  int tid = threadIdx.x;
  int d = blockIdx.x*16 + (tid >> 4);
  if (d >= nseg) return;
  int q = (tid & 15) << 2;
  float4 a = make_float4(0,0,0,0);
  int j1 = offs[d+1];
  for (int j = offs[d]; j < j1; ++j) {
    int s = src[perm[j]];
    a = add4(a, ld4(&msg[(size_t)s*64 + q]));
  }
  size_t o = (size_t)d*64 + q;
  float m = mask[d], im = 1.f - m;
  float4 cav = ld4(&ca[o]), fev = ld4(&fe[o]), cv = ld4(&cui[o]);
  st4(&outb[o], make_float4((m*(a.x*cav.x) + im*fev.x)*cv.x,
                            (m*(a.y*cav.y) + im*fev.y)*cv.y,
                            (m*(a.z*cav.z) + im*fev.z)*cv.z,
                            (m*(a.w*cav.w) + im*fev.w)*cv.w));
}

__global__ __launch_bounds__(256) void gather3(
    const int* __restrict__ offs, const int* __restrict__ perm,
    const int* __restrict__ src, const int* __restrict__ rating,
    const float* __restrict__ msgA, const float* __restrict__ msgB,
    const float* __restrict__ msgC,
    const float* __restrict__ sigA, const float* __restrict__ sigB,
    const float* __restrict__ sigC,
    const float* __restrict__ cmul,
    float* __restrict__ outA, float* __restrict__ outB, float* __restrict__ outC,
    int nseg)
{
  int tid = threadIdx.x;
  int d = blockIdx.x*16 + (tid >> 4);
  if (d >= nseg) return;
  int q = (tid & 15) << 2;
  float4 a0 = make_float4(0,0,0,0), a1 = a0, a2 = a0;
  int j1 = offs[d+1];
  for (int j = offs[d]; j < j1; ++j) {
    int e = perm[j];
    int s = src[e];
    int r = rating[e];
    size_t so = (size_t)s*64 + q;
    int ro = r*64 + q;
    a0 = add4(a0, mul4(ld4(&msgA[so]), ld4(&sigA[ro])));
    a1 = add4(a1, mul4(ld4(&msgB[so]), ld4(&sigB[ro])));
    a2 = add4(a2, mul4(ld4(&msgC[so]), ld4(&sigC[ro])));
  }
  size_t o = (size_t)d*64 + q;
  float4 c = ld4(&cmul[o]);
  st4(&outA[o], mul4(a0, c));
  st4(&outB[o], mul4(a1, c));
  st4(&outC[o], mul4(a2, c));
}

// batched fe5/re gather: z = blockIdx.y
#define FE5Z 10
struct Fe5Meta {
  const int* offs[FE5Z]; const int* perm[FE5Z]; const int* src[FE5Z];
  const float* re[FE5Z]; const float* w[FE5Z]; const float* cuiS[FE5Z];
  const float* cmulD[FE5Z]; float* outA[FE5Z]; float* outB[FE5Z]; int nseg[FE5Z];
};

__global__ __launch_bounds__(256) void gather_fe5_batched(Fe5Meta m)
{
  int z = blockIdx.y;
  int tid = threadIdx.x;
  int d = blockIdx.x*16 + (tid >> 4);
  if (d >= m.nseg[z]) return;
  int q = (tid & 15) << 2;
  const int* offs = m.offs[z]; const int* perm = m.perm[z]; const int* src = m.src[z];
  const float* re = m.re[z]; const float* w = m.w[z]; const float* cuiS = m.cuiS[z];
  float4 a0 = make_float4(0,0,0,0), a1 = a0;
  int j1 = offs[d+1];
  for (int j = offs[d]; j < j1; ++j) {
    int e = perm[j];
    int s = src[e];
    float4 rv = ld4(&re[(size_t)e*64 + q]);
    float4 cv = ld4(&cuiS[(size_t)s*64 + q]);
    float4 wv = ld4(&w[(size_t)s*64 + q]);
    a0 = add4(a0, mul4(add4(wv, rv), cv));
    a1 = add4(a1, mul4(rv, cv));
  }
  float4 c = ld4(&m.cmulD[z][(size_t)d*64 + q]);
  size_t o = (size_t)d*320 + q;
  st4(&m.outA[z][o], mul4(a0, c));
  st4(&m.outB[z][o], mul4(a1, c));
}

extern "C" void kernel_launch(void* const* d_in, const int* in_sizes, int n_in,
                              void* d_out, int out_size, void* d_ws, size_t ws_size,
                              hipStream_t stream)
{
  (void)in_sizes; (void)n_in; (void)out_size;
  auto F = [&](int i){ return (const float*)d_in[i]; };
  auto Ix = [&](int i){ return (const int*)d_in[i]; };

  const float* feature1 = F(0);
  const float* feature2 = F(1);
  const float* feature3 = F(2);
  const float* weightK[5]   = {F(3),F(4),F(5),F(6),F(7)};
  const float* W_review1 = F(8);
  const float* W_review2 = F(9);
  const float* rating_emb[6] = {F(10),F(11),F(12),F(13),F(14),F(15)};
  const float* W_aspect  = F(16);
  const float* W_aspect2 = F(17);
  const float* W_count_user = F(18);
  const float* b_count_user = F(19);
  const float* W_count_item = F(20);
  const float* b_count_item = F(21);
  const float* aspect_fe  = F(22);
  const float* aspect_cau = F(23);
  const float* aspect_cai = F(24);
  const float* user_cau = F(25);
  const float* user_cui = F(26);
  const float* item_cai = F(27);
  const float* item_ciu = F(28);
  const float* user_cuiK[5] = {F(29),F(31),F(33),F(35),F(37)};
  const float* item_ciuK[5] = {F(30),F(32),F(34),F(36),F(38)};
  const float* user_mask = F(39);
  const float* item_mask = F(40);
  const float* user_aspect_count = F(41);
  const float* item_aspect_count = F(42);
  const float* uiK_review[5] = {F(45),F(47),F(49),F(51),F(53)};
  const float* iuK_review[5] = {F(46),F(48),F(50),F(52),F(54)};
  const int* au_src = Ix(55); const int* au_dst = Ix(56);
  const int* ai_src = Ix(57); const int* ai_dst = Ix(58);
  const int* ui_src = Ix(59); const int* ui_dst = Ix(60); const int* ui_rating = Ix(61);
  const int* iu_src = Ix(62); const int* iu_dst = Ix(63); const int* iu_rating = Ix(64);
  const int* uiK_src[5] = {Ix(65),Ix(69),Ix(73),Ix(77),Ix(81)};
  const int* uiK_dst[5] = {Ix(66),Ix(70),Ix(74),Ix(78),Ix(82)};
  const int* iuK_src[5] = {Ix(67),Ix(71),Ix(75),Ix(79),Ix(83)};
  const int* iuK_dst[5] = {Ix(68),Ix(72),Ix(76),Ix(80),Ix(84)};

  float* out  = (float*)d_out;
  float* out2 = out + (size_t)N_CNT*64;
  float* out3 = out + 2*(size_t)N_CNT*64;
  float* out4 = out + 3*(size_t)N_CNT*64;              // (N,320)
  float* out5 = out + 8*(size_t)N_CNT*64;              // (N,320)

  // ---- workspace layout (floats) ----
  float* ws = (float*)d_ws;
  size_t off = 0;
  auto alloc = [&](size_t n){ float* p = ws + off; off += (n + 3) & ~(size_t)3; return p; };
  float* sigt   = alloc(6*320);
  float* msg_au = alloc((size_t)A_CNT*64);
  float* msg_ai = alloc((size_t)A_CNT*64);
  float* h_u_a  = alloc((size_t)U_CNT*64);
  float* h_i_a  = alloc((size_t)I_CNT*64);
  float* g_u    = alloc((size_t)U_CNT*64);
  float* g_i    = alloc((size_t)I_CNT*64);
  float* fe1c   = alloc((size_t)N_CNT*64);

  // int region: [cnt x14][bsum][offs x14][cur x14][perm x14]
  int* ibase = (int*)(ws + off);
  const int* l_dst[NLIST] = {au_dst, ai_dst, ui_dst, iu_dst,
                             uiK_dst[0],uiK_dst[1],uiK_dst[2],uiK_dst[3],uiK_dst[4],
                             iuK_dst[0],iuK_dst[1],iuK_dst[2],iuK_dst[3],iuK_dst[4]};
  int l_E[NLIST]    = {EAU,EAU,EUI,EUI, ER,ER,ER,ER,ER, ER,ER,ER,ER,ER};
  int l_nseg[NLIST] = {U_CNT,I_CNT,I_CNT,U_CNT, I_CNT,I_CNT,I_CNT,I_CNT,I_CNT,
                       U_CNT,U_CNT,U_CNT,U_CNT,U_CNT};
  CsrMeta cm;
  size_t io = 0;
  for (int l = 0; l < NLIST; ++l) { cm.cnt[l] = ibase + io; io += l_nseg[l]; }
  int* bsum = ibase + io; io += NLIST*32;
  size_t zero_ints = (io + 3) & ~(size_t)3;            // cnt + bsum span
  for (int l = 0; l < NLIST; ++l) { cm.offs[l] = ibase + io; io += l_nseg[l] + 1; }
  for (int l = 0; l < NLIST; ++l) { cm.cur[l]  = ibase + io; io += l_nseg[l]; }
  for (int l = 0; l < NLIST; ++l) { cm.perm[l] = ibase + io; io += l_E[l]; }
  for (int l = 0; l < NLIST; ++l) { cm.dst[l]=l_dst[l]; cm.E[l]=l_E[l]; cm.nseg[l]=l_nseg[l]; }
  off += (io + 3) & ~(size_t)3;

  // region X (aliased): split-K partials, then re buffers (stream-ordered lifetimes)
  float* xbase = ws + off;
  const size_t reN = (size_t)ER*64;
  // tier A: SPLIT=8, 10 re buffers; tier C: SPLIT=4, 2 re buffers
  size_t xA = 10*reN;                                   // 153.6 MB > 8*35000*64 (71.7 MB)
  size_t partA = (size_t)8*N_CNT*64;
  if (partA > xA) xA = partA;
  size_t needA_bytes = (off + xA) * 4;
  bool tierA = ws_size >= needA_bytes;
  const int SPLIT = tierA ? 8 : 4;
  const int NRE   = tierA ? 10 : 2;

  float* part_u = xbase;                                // SPLIT*U*64
  float* part_i = xbase + (size_t)SPLIT*U_CNT*64;       // SPLIT*I*64
  float* reb[10];
  for (int j = 0; j < NRE; ++j) reb[j] = xbase + (size_t)j*reN;

  const int BS = 256;
  const int gE    = (EAU + BS-1)/BS;                    // 1172
  const int gU16  = (U_CNT + 15)/16;                    // 1250
  const int gI16  = (I_CNT + 15)/16;                    // 938
  const int gN16  = (N_CNT*16 + BS-1)/BS;
  const int gRu16 = (U_CNT*16 + BS-1)/BS;               // 1250
  const int gRi16 = (I_CNT*16 + BS-1)/BS;               // 938
  const int gGu   = (U_CNT + 63)/64;                    // 313
  const int gGi   = (I_CNT + 63)/64;                    // 235
  const int gGr   = (ER + 63)/64;                       // 938
  const int gGa   = A_CNT/64;                           // 32
  const int gScanL = (U_CNT + 1023)/1024;               // 20
  const int gScanA = (U_CNT + BS-1)/BS;                 // 79

  // ---- CSR build ----
  zero_kernel<<<(int)((zero_ints/4 + BS-1)/BS), BS, 0, stream>>>((float4*)ibase, (int)(zero_ints/4));
  hist_batched<<<dim3(gE, NLIST), BS, 0, stream>>>(cm);
  scan_local<<<dim3(gScanL, NLIST), BS, 0, stream>>>(cm, bsum);
  scan_bsum<<<NLIST, 64, 0, stream>>>(cm, bsum);
  scan_add<<<dim3(gScanA, NLIST), BS, 0, stream>>>(cm, bsum);
  fill_batched<<<dim3(gE, NLIST), BS, 0, stream>>>(cm);

  // ---- small precompute ----
  sigtab_kernel<<<8, BS, 0, stream>>>(rating_emb[0],rating_emb[1],rating_emb[2],
                                      rating_emb[3],rating_emb[4],rating_emb[5], sigt);
  fe1c_kernel<<<gN16, BS, 0, stream>>>(feature1, user_cui, item_ciu, fe1c);

  // ---- split-K count GEMMs + fused reduce/blend epilogue ----
  gemm_splitk<<<dim3(gGu, SPLIT), BS, 0, stream>>>(user_aspect_count, U_CNT, W_count_user, part_u);
  gemm_splitk<<<dim3(gGi, SPLIT), BS, 0, stream>>>(item_aspect_count, I_CNT, W_count_item, part_i);
  reduce_blend<<<gRu16, BS, 0, stream>>>(part_u, U_CNT, SPLIT, b_count_user,
      user_mask, user_cau, feature3, user_cui, g_u);
  reduce_blend<<<gRi16, BS, 0, stream>>>(part_i, I_CNT, SPLIT, b_count_item,
      item_mask, item_cai, feature3 + (size_t)U_CNT*64, item_ciu, g_i);

  // ---- K=64 GEMMs ----
  K64Meta km;
  // aspect GEMMs always present
  km.A[0]=aspect_fe; km.W[0]=W_aspect;  km.mulp[0]=aspect_cau; km.C[0]=msg_au; km.M[0]=A_CNT;
  km.A[1]=aspect_fe; km.W[1]=W_aspect2; km.mulp[1]=aspect_cai; km.C[1]=msg_ai; km.M[1]=A_CNT;
  if (tierA) {
    for (int k = 0; k < 5; ++k) {
      km.A[2+k]=uiK_review[k]; km.W[2+k]=W_review1; km.mulp[2+k]=nullptr; km.C[2+k]=reb[k];   km.M[2+k]=ER;
      km.A[7+k]=iuK_review[k]; km.W[7+k]=W_review2; km.mulp[7+k]=nullptr; km.C[7+k]=reb[5+k]; km.M[7+k]=ER;
    }
    gemm_k64<<<dim3(gGr, 12), BS, 0, stream>>>(km);
  } else {
    gemm_k64<<<dim3(gGa, 2), BS, 0, stream>>>(km);
  }

  // ---- aspect gathers with blend epilogue ----
  gather_blend<<<gU16, BS, 0, stream>>>(cm.offs[0], cm.perm[0], au_src, msg_au,
      user_mask, user_cau, feature2, user_cui, h_u_a, U_CNT);
  gather_blend<<<gI16, BS, 0, stream>>>(cm.offs[1], cm.perm[1], ai_src, msg_ai,
      item_mask, item_cai, feature2 + (size_t)U_CNT*64, item_ciu, h_i_a, I_CNT);

  // ---- fused 3-acc gathers -> outputs 1..3 ----
  gather3<<<gI16, BS, 0, stream>>>(cm.offs[2], cm.perm[2], ui_src, ui_rating,
      h_u_a, g_u, fe1c, sigt + 0*320, sigt + 2*320, sigt + 4*320,
      item_ciu, out + (size_t)U_CNT*64, out2 + (size_t)U_CNT*64, out3 + (size_t)U_CNT*64, I_CNT);
  gather3<<<gU16, BS, 0, stream>>>(cm.offs[3], cm.perm[3], iu_src, iu_rating,
      h_i_a, g_i, fe1c + (size_t)U_CNT*64, sigt + 1*320, sigt + 3*320, sigt + 5*320,
      user_cui, out, out2, out3, U_CNT);

  // ---- fe5/re branch ----
  auto fill_fe5 = [&](Fe5Meta& fm, int z, int k, const float* rebuf_ui, const float* rebuf_iu){
    // z slot for ui-side (dst=items)
    fm.offs[z]=cm.offs[4+k]; fm.perm[z]=cm.perm[4+k]; fm.src[z]=uiK_src[k];
    fm.re[z]=rebuf_ui; fm.w[z]=weightK[k]; fm.cuiS[z]=user_cuiK[k]; fm.cmulD[z]=item_ciuK[k];
    fm.outA[z]=out4 + (size_t)U_CNT*320 + (size_t)k*64;
    fm.outB[z]=out5 + (size_t)U_CNT*320 + (size_t)k*64;
    fm.nseg[z]=I_CNT;
    // z+1 slot for iu-side (dst=users)
    fm.offs[z+1]=cm.offs[9+k]; fm.perm[z+1]=cm.perm[9+k]; fm.src[z+1]=iuK_src[k];
    fm.re[z+1]=rebuf_iu; fm.w[z+1]=weightK[k] + (size_t)U_CNT*64;
    fm.cuiS[z+1]=item_ciuK[k]; fm.cmulD[z+1]=user_cuiK[k];
    fm.outA[z+1]=out4 + (size_t)k*64;
    fm.outB[z+1]=out5 + (size_t)k*64;
    fm.nseg[z+1]=U_CNT;
  };

  if (tierA) {
    Fe5Meta fm;
    for (int k = 0; k < 5; ++k) fill_fe5(fm, 2*k, k, reb[k], reb[5+k]);
    gather_fe5_batched<<<dim3(gU16, 10), BS, 0, stream>>>(fm);
  } else {
    for (int k = 0; k < 5; ++k) {
      K64Meta kr;
      kr.A[0]=uiK_review[k]; kr.W[0]=W_review1; kr.mulp[0]=nullptr; kr.C[0]=reb[0]; kr.M[0]=ER;
      kr.A[1]=iuK_review[k]; kr.W[1]=W_review2; kr.mulp[1]=nullptr; kr.C[1]=reb[1]; kr.M[1]=ER;
      gemm_k64<<<dim3(gGr, 2), BS, 0, stream>>>(kr);
      Fe5Meta fm;
      fill_fe5(fm, 0, k, reb[0], reb[1]);
      gather_fe5_batched<<<dim3(gU16, 2), BS, 0, stream>>>(fm);
    }
  }
}

// Round 4
// 562.084 us; speedup vs baseline: 6.5945x; 1.2178x over previous
//
#include <hip/hip_runtime.h>
#include <cstddef>

#define U_CNT 20000
#define I_CNT 15000
#define N_CNT 35000
#define A_CNT 2048
#define NC_K  2048
#define EAU   300000
#define EUI   300000
#define ER    60000
#define NLIST 14

__device__ __forceinline__ float4 ld4(const float* p){ return *reinterpret_cast<const float4*>(p); }
__device__ __forceinline__ void st4(float* p, float4 v){ *reinterpret_cast<float4*>(p) = v; }
__device__ __forceinline__ float4 mul4(float4 a, float4 b){ return make_float4(a.x*b.x, a.y*b.y, a.z*b.z, a.w*b.w); }
__device__ __forceinline__ float4 add4(float4 a, float4 b){ return make_float4(a.x+b.x, a.y+b.y, a.z+b.z, a.w+b.w); }
__device__ __forceinline__ float4 fmas4(float s, float4 b, float4 c){
  return make_float4(fmaf(s,b.x,c.x), fmaf(s,b.y,c.y), fmaf(s,b.z,c.z), fmaf(s,b.w,c.w));
}

// ---------------- linked-list edge index build ----------------
// node[i] = (prev_edge, src | rating<<20); head[d] = last edge with dst d.
struct BuildMeta {
  const int* src[NLIST]; const int* dst[NLIST]; const int* rating[NLIST];
  int2* node[NLIST]; int* head[NLIST]; int E[NLIST];
};

__global__ __launch_bounds__(256) void fill_m1(int4* __restrict__ p, int n4)
{
  int gid = blockIdx.x*256 + threadIdx.x;
  if (gid < n4) p[gid] = make_int4(-1,-1,-1,-1);
}

__global__ __launch_bounds__(256) void build_batched(BuildMeta m)
{
  int li = blockIdx.y;
  int i = blockIdx.x*256 + threadIdx.x;
  if (i >= m.E[li]) return;
  int d = m.dst[li][i];
  int pay = m.src[li][i];
  const int* rat = m.rating[li];
  if (rat) pay |= rat[i] << 20;
  int prev = atomicExch(&m.head[li][d], i);
  m.node[li][i] = make_int2(prev, pay);
}

// ---------------- small precompute ----------------
__global__ __launch_bounds__(256) void sigtab_kernel(
    const float* __restrict__ e0, const float* __restrict__ e1,
    const float* __restrict__ e2, const float* __restrict__ e3,
    const float* __restrict__ e4, const float* __restrict__ e5,
    float* __restrict__ out)
{
  int i = blockIdx.x*256 + threadIdx.x;
  if (i >= 6*320) return;
  int k = i / 320, j = i % 320;
  const float* e = (k==0)?e0:(k==1)?e1:(k==2)?e2:(k==3)?e3:(k==4)?e4:e5;
  out[i] = 1.f/(1.f + __expf(-e[j]));
}

__global__ __launch_bounds__(256) void fe1c_kernel(
    const float* __restrict__ f1, const float* __restrict__ cui,
    const float* __restrict__ ciu, float* __restrict__ out)
{
  int gid = blockIdx.x*256 + threadIdx.x;
  if (gid >= N_CNT*16) return;
  int n = gid >> 4, q = (gid & 15) << 2;
  size_t o = (size_t)n*64 + q;
  float4 v = ld4(&f1[o]);
  float4 c = (n < U_CNT) ? ld4(&cui[o]) : ld4(&ciu[(size_t)(n-U_CNT)*64 + q]);
  st4(&out[o], mul4(v, c));
}

// ---------------------------------------------------------------------------
// Batched K=64 GEMM: C[z] = A[z](M[z],64) @ W[z](64,64) (* mulp[z]) — z = blockIdx.y
// ---------------------------------------------------------------------------
#define K64Z 12
struct K64Meta { const float* A[K64Z]; const float* W[K64Z]; const float* mulp[K64Z];
                 float* C[K64Z]; int M[K64Z]; };

__global__ __launch_bounds__(256) void gemm_k64(K64Meta m)
{
  int z = blockIdx.y;
  int M = m.M[z];
  int r0 = blockIdx.x * 64;
  if (r0 >= M) return;
  const float* __restrict__ A = m.A[z];
  const float* __restrict__ W = m.W[z];
  __shared__ float As[64][36];
  __shared__ float Ws[32][64];
  const int t  = threadIdx.x;
  const int ty = t >> 4, tx = t & 15;
  float4 acc0 = make_float4(0,0,0,0), acc1 = acc0, acc2 = acc0, acc3 = acc0;

  for (int k0 = 0; k0 < 64; k0 += 32) {
    __syncthreads();
    #pragma unroll
    for (int i = 0; i < 2; ++i) {
      int f = t + i*256;
      int row = f >> 3, caa = (f & 7) << 2;
      float4 v = make_float4(0.f,0.f,0.f,0.f);
      int r = r0 + row;
      if (r < M) v = ld4(&A[(size_t)r*64 + k0 + caa]);
      st4(&As[row][caa], v);
      int kk = f >> 4, cb = (f & 15) << 2;
      st4(&Ws[kk][cb], ld4(&W[(size_t)(k0+kk)*64 + cb]));
    }
    __syncthreads();
    #pragma unroll
    for (int kk = 0; kk < 32; kk += 4) {
      float4 a0 = ld4(&As[ty*4+0][kk]);
      float4 a1 = ld4(&As[ty*4+1][kk]);
      float4 a2 = ld4(&As[ty*4+2][kk]);
      float4 a3 = ld4(&As[ty*4+3][kk]);
      float a0v[4] = {a0.x,a0.y,a0.z,a0.w};
      float a1v[4] = {a1.x,a1.y,a1.z,a1.w};
      float a2v[4] = {a2.x,a2.y,a2.z,a2.w};
      float a3v[4] = {a3.x,a3.y,a3.z,a3.w};
      #pragma unroll
      for (int j = 0; j < 4; ++j) {
        float4 wv = ld4(&Ws[kk+j][tx<<2]);
        acc0 = fmas4(a0v[j], wv, acc0);
        acc1 = fmas4(a1v[j], wv, acc1);
        acc2 = fmas4(a2v[j], wv, acc2);
        acc3 = fmas4(a3v[j], wv, acc3);
      }
    }
  }

  const float* mulp = m.mulp[z];
  float* C = m.C[z];
  float4 accs[4] = {acc0,acc1,acc2,acc3};
  #pragma unroll
  for (int i = 0; i < 4; ++i) {
    int r = r0 + ty*4 + i;
    if (r < M) {
      float4 v = accs[i];
      size_t o = (size_t)r*64 + (tx<<2);
      if (mulp) v = mul4(v, ld4(&mulp[o]));
      st4(&C[o], v);
    }
  }
}

// ---------------------------------------------------------------------------
// Split-K GEMM for K=2048
// ---------------------------------------------------------------------------
__global__ __launch_bounds__(256) void gemm_splitk(
    const float* __restrict__ A, int M,
    const float* __restrict__ W, float* __restrict__ part)
{
  const int nsplit = gridDim.y;
  const int sp = blockIdx.y;
  const int kchunk = NC_K / nsplit;
  const int k0base = sp * kchunk;
  __shared__ float As[64][36];
  __shared__ float Ws[32][64];
  const int t  = threadIdx.x;
  const int r0 = blockIdx.x * 64;
  const int ty = t >> 4, tx = t & 15;
  float4 acc0 = make_float4(0,0,0,0), acc1 = acc0, acc2 = acc0, acc3 = acc0;

  for (int k0 = k0base; k0 < k0base + kchunk; k0 += 32) {
    __syncthreads();
    #pragma unroll
    for (int i = 0; i < 2; ++i) {
      int f = t + i*256;
      int row = f >> 3, caa = (f & 7) << 2;
      float4 v = make_float4(0.f,0.f,0.f,0.f);
      int r = r0 + row;
      if (r < M) v = ld4(&A[(size_t)r*NC_K + k0 + caa]);
      st4(&As[row][caa], v);
      int kk = f >> 4, cb = (f & 15) << 2;
      st4(&Ws[kk][cb], ld4(&W[(size_t)(k0+kk)*64 + cb]));
    }
    __syncthreads();
    #pragma unroll
    for (int kk = 0; kk < 32; kk += 4) {
      float4 a0 = ld4(&As[ty*4+0][kk]);
      float4 a1 = ld4(&As[ty*4+1][kk]);
      float4 a2 = ld4(&As[ty*4+2][kk]);
      float4 a3 = ld4(&As[ty*4+3][kk]);
      float a0v[4] = {a0.x,a0.y,a0.z,a0.w};
      float a1v[4] = {a1.x,a1.y,a1.z,a1.w};
      float a2v[4] = {a2.x,a2.y,a2.z,a2.w};
      float a3v[4] = {a3.x,a3.y,a3.z,a3.w};
      #pragma unroll
      for (int j = 0; j < 4; ++j) {
        float4 wv = ld4(&Ws[kk+j][tx<<2]);
        acc0 = fmas4(a0v[j], wv, acc0);
        acc1 = fmas4(a1v[j], wv, acc1);
        acc2 = fmas4(a2v[j], wv, acc2);
        acc3 = fmas4(a3v[j], wv, acc3);
      }
    }
  }

  float4 accs[4] = {acc0,acc1,acc2,acc3};
  float* base = part + (size_t)sp * M * 64;
  #pragma unroll
  for (int i = 0; i < 4; ++i) {
    int r = r0 + ty*4 + i;
    if (r < M) st4(&base[(size_t)r*64 + (tx<<2)], accs[i]);
  }
}

// reduce splits + bias + blend epilogue
__global__ __launch_bounds__(256) void reduce_blend(
    const float* __restrict__ part, int M, int nsplit,
    const float* __restrict__ bias, const float* __restrict__ mask,
    const float* __restrict__ ca, const float* __restrict__ fe,
    const float* __restrict__ cui, float* __restrict__ outb)
{
  int gid = blockIdx.x*256 + threadIdx.x;
  if (gid >= M*16) return;
  int n = gid >> 4, q = (gid & 15) << 2;
  float4 a = ld4(&bias[q]);
  for (int s = 0; s < nsplit; ++s)
    a = add4(a, ld4(&part[((size_t)s*M + n)*64 + q]));
  size_t o = (size_t)n*64 + q;
  float m = mask[n], im = 1.f - m;
  float4 cav = ld4(&ca[o]), fev = ld4(&fe[o]), cv = ld4(&cui[o]);
  st4(&outb[o], make_float4((m*(a.x*cav.x) + im*fev.x)*cv.x,
                            (m*(a.y*cav.y) + im*fev.y)*cv.y,
                            (m*(a.z*cav.z) + im*fev.z)*cv.z,
                            (m*(a.w*cav.w) + im*fev.w)*cv.w));
}

// ---------------- chain gathers (no atomics, no perm) ----------------
// 16 lanes per dst row; all 16 lanes walk the same chain (broadcast node reads).

__global__ __launch_bounds__(256) void gather_blend(
    const int* __restrict__ head, const int2* __restrict__ node,
    const float* __restrict__ msg,
    const float* __restrict__ mask, const float* __restrict__ ca,
    const float* __restrict__ fe, const float* __restrict__ cui,
    float* __restrict__ outb, int nseg)
{
  int tid = threadIdx.x;
  int d = blockIdx.x*16 + (tid >> 4);
  if (d >= nseg) return;
  int q = (tid & 15) << 2;
  float4 a = make_float4(0,0,0,0);
  for (int cur = head[d]; cur >= 0; ) {
    int2 nd = node[cur];
    cur = nd.x;
    a = add4(a, ld4(&msg[(size_t)nd.y*64 + q]));
  }
  size_t o = (size_t)d*64 + q;
  float m = mask[d], im = 1.f - m;
  float4 cav = ld4(&ca[o]), fev = ld4(&fe[o]), cv = ld4(&cui[o]);
  st4(&outb[o], make_float4((m*(a.x*cav.x) + im*fev.x)*cv.x,
                            (m*(a.y*cav.y) + im*fev.y)*cv.y,
                            (m*(a.z*cav.z) + im*fev.z)*cv.z,
                            (m*(a.w*cav.w) + im*fev.w)*cv.w));
}

__global__ __launch_bounds__(256) void gather3(
    const int* __restrict__ head, const int2* __restrict__ node,
    const float* __restrict__ msgA, const float* __restrict__ msgB,
    const float* __restrict__ msgC,
    const float* __restrict__ sigA, const float* __restrict__ sigB,
    const float* __restrict__ sigC,
    const float* __restrict__ cmul,
    float* __restrict__ outA, float* __restrict__ outB, float* __restrict__ outC,
    int nseg)
{
  int tid = threadIdx.x;
  int d = blockIdx.x*16 + (tid >> 4);
  if (d >= nseg) return;
  int q = (tid & 15) << 2;
  float4 a0 = make_float4(0,0,0,0), a1 = a0, a2 = a0;
  for (int cur = head[d]; cur >= 0; ) {
    int2 nd = node[cur];
    cur = nd.x;
    int s = nd.y & 0xFFFFF;
    int r = nd.y >> 20;
    size_t so = (size_t)s*64 + q;
    int ro = r*64 + q;
    a0 = add4(a0, mul4(ld4(&msgA[so]), ld4(&sigA[ro])));
    a1 = add4(a1, mul4(ld4(&msgB[so]), ld4(&sigB[ro])));
    a2 = add4(a2, mul4(ld4(&msgC[so]), ld4(&sigC[ro])));
  }
  size_t o = (size_t)d*64 + q;
  float4 c = ld4(&cmul[o]);
  st4(&outA[o], mul4(a0, c));
  st4(&outB[o], mul4(a1, c));
  st4(&outC[o], mul4(a2, c));
}

#define FE5Z 10
struct Fe5Meta {
  const int* head[FE5Z]; const int2* node[FE5Z];
  const float* re[FE5Z]; const float* w[FE5Z]; const float* cuiS[FE5Z];
  const float* cmulD[FE5Z]; float* outA[FE5Z]; float* outB[FE5Z]; int nseg[FE5Z];
};

__global__ __launch_bounds__(256) void gather_fe5_batched(Fe5Meta m)
{
  int z = blockIdx.y;
  int tid = threadIdx.x;
  int d = blockIdx.x*16 + (tid >> 4);
  if (d >= m.nseg[z]) return;
  int q = (tid & 15) << 2;
  const int2* __restrict__ node = m.node[z];
  const float* __restrict__ re = m.re[z];
  const float* __restrict__ w = m.w[z];
  const float* __restrict__ cuiS = m.cuiS[z];
  float4 a0 = make_float4(0,0,0,0), a1 = a0;
  for (int cur = m.head[z][d]; cur >= 0; ) {
    int2 nd = node[cur];
    int e = cur;
    cur = nd.x;
    int s = nd.y;
    float4 rv = ld4(&re[(size_t)e*64 + q]);
    float4 cv = ld4(&cuiS[(size_t)s*64 + q]);
    float4 wv = ld4(&w[(size_t)s*64 + q]);
    a0 = add4(a0, mul4(add4(wv, rv), cv));
    a1 = add4(a1, mul4(rv, cv));
  }
  float4 c = ld4(&m.cmulD[z][(size_t)d*64 + q]);
  size_t o = (size_t)d*320 + q;
  st4(&m.outA[z][o], mul4(a0, c));
  st4(&m.outB[z][o], mul4(a1, c));
}

extern "C" void kernel_launch(void* const* d_in, const int* in_sizes, int n_in,
                              void* d_out, int out_size, void* d_ws, size_t ws_size,
                              hipStream_t stream)
{
  (void)in_sizes; (void)n_in; (void)out_size;
  auto F = [&](int i){ return (const float*)d_in[i]; };
  auto Ix = [&](int i){ return (const int*)d_in[i]; };

  const float* feature1 = F(0);
  const float* feature2 = F(1);
  const float* feature3 = F(2);
  const float* weightK[5]   = {F(3),F(4),F(5),F(6),F(7)};
  const float* W_review1 = F(8);
  const float* W_review2 = F(9);
  const float* rating_emb[6] = {F(10),F(11),F(12),F(13),F(14),F(15)};
  const float* W_aspect  = F(16);
  const float* W_aspect2 = F(17);
  const float* W_count_user = F(18);
  const float* b_count_user = F(19);
  const float* W_count_item = F(20);
  const float* b_count_item = F(21);
  const float* aspect_fe  = F(22);
  const float* aspect_cau = F(23);
  const float* aspect_cai = F(24);
  const float* user_cau = F(25);
  const float* user_cui = F(26);
  const float* item_cai = F(27);
  const float* item_ciu = F(28);
  const float* user_cuiK[5] = {F(29),F(31),F(33),F(35),F(37)};
  const float* item_ciuK[5] = {F(30),F(32),F(34),F(36),F(38)};
  const float* user_mask = F(39);
  const float* item_mask = F(40);
  const float* user_aspect_count = F(41);
  const float* item_aspect_count = F(42);
  const float* uiK_review[5] = {F(45),F(47),F(49),F(51),F(53)};
  const float* iuK_review[5] = {F(46),F(48),F(50),F(52),F(54)};
  const int* au_src = Ix(55); const int* au_dst = Ix(56);
  const int* ai_src = Ix(57); const int* ai_dst = Ix(58);
  const int* ui_src = Ix(59); const int* ui_dst = Ix(60); const int* ui_rating = Ix(61);
  const int* iu_src = Ix(62); const int* iu_dst = Ix(63); const int* iu_rating = Ix(64);
  const int* uiK_src[5] = {Ix(65),Ix(69),Ix(73),Ix(77),Ix(81)};
  const int* uiK_dst[5] = {Ix(66),Ix(70),Ix(74),Ix(78),Ix(82)};
  const int* iuK_src[5] = {Ix(67),Ix(71),Ix(75),Ix(79),Ix(83)};
  const int* iuK_dst[5] = {Ix(68),Ix(72),Ix(76),Ix(80),Ix(84)};

  float* out  = (float*)d_out;
  float* out2 = out + (size_t)N_CNT*64;
  float* out3 = out + 2*(size_t)N_CNT*64;
  float* out4 = out + 3*(size_t)N_CNT*64;              // (N,320)
  float* out5 = out + 8*(size_t)N_CNT*64;              // (N,320)

  // ---- workspace layout (floats) ----
  float* ws = (float*)d_ws;
  size_t off = 0;
  auto alloc = [&](size_t n){ float* p = ws + off; off += (n + 3) & ~(size_t)3; return p; };
  float* sigt   = alloc(6*320);
  float* msg_au = alloc((size_t)A_CNT*64);
  float* msg_ai = alloc((size_t)A_CNT*64);
  float* h_u_a  = alloc((size_t)U_CNT*64);
  float* h_i_a  = alloc((size_t)I_CNT*64);
  float* g_u    = alloc((size_t)U_CNT*64);
  float* g_i    = alloc((size_t)I_CNT*64);
  float* fe1c   = alloc((size_t)N_CNT*64);

  // ---- int region: [head x14][node x14] ----
  // lists: 0=au(U) 1=ai(I) 2=ui(I) 3=iu(U) 4..8=uiK(I) 9..13=iuK(U)
  const int* l_src[NLIST] = {au_src, ai_src, ui_src, iu_src,
                             uiK_src[0],uiK_src[1],uiK_src[2],uiK_src[3],uiK_src[4],
                             iuK_src[0],iuK_src[1],iuK_src[2],iuK_src[3],iuK_src[4]};
  const int* l_dst[NLIST] = {au_dst, ai_dst, ui_dst, iu_dst,
                             uiK_dst[0],uiK_dst[1],uiK_dst[2],uiK_dst[3],uiK_dst[4],
                             iuK_dst[0],iuK_dst[1],iuK_dst[2],iuK_dst[3],iuK_dst[4]};
  const int* l_rat[NLIST] = {nullptr, nullptr, ui_rating, iu_rating,
                             nullptr,nullptr,nullptr,nullptr,nullptr,
                             nullptr,nullptr,nullptr,nullptr,nullptr};
  int l_E[NLIST]    = {EAU,EAU,EUI,EUI, ER,ER,ER,ER,ER, ER,ER,ER,ER,ER};
  int l_nseg[NLIST] = {U_CNT,I_CNT,I_CNT,U_CNT, I_CNT,I_CNT,I_CNT,I_CNT,I_CNT,
                       U_CNT,U_CNT,U_CNT,U_CNT,U_CNT};

  int* ibase = (int*)(ws + off);
  BuildMeta bm;
  size_t io = 0;
  for (int l = 0; l < NLIST; ++l) { bm.head[l] = ibase + io; io += l_nseg[l]; }
  size_t head_ints = io;                                // 245000 (divisible by 4)
  for (int l = 0; l < NLIST; ++l) { bm.node[l] = (int2*)(ibase + io); io += 2*(size_t)l_E[l]; }
  for (int l = 0; l < NLIST; ++l) { bm.src[l]=l_src[l]; bm.dst[l]=l_dst[l];
                                    bm.rating[l]=l_rat[l]; bm.E[l]=l_E[l]; }
  off += (io + 3) & ~(size_t)3;

  // region X (aliased): split-K partials, then re buffers (stream-ordered lifetimes)
  float* xbase = ws + off;
  const size_t reN = (size_t)ER*64;
  size_t xA = 10*reN;
  size_t partA = (size_t)8*N_CNT*64;
  if (partA > xA) xA = partA;
  size_t needA_bytes = (off + xA) * 4;
  bool tierA = ws_size >= needA_bytes;
  const int SPLIT = tierA ? 8 : 4;
  const int NRE   = tierA ? 10 : 2;

  float* part_u = xbase;
  float* part_i = xbase + (size_t)SPLIT*U_CNT*64;
  float* reb[10];
  for (int j = 0; j < NRE; ++j) reb[j] = xbase + (size_t)j*reN;

  const int BS = 256;
  const int gE    = (EAU + BS-1)/BS;                    // 1172 (covers max E; smaller lists guard)
  const int gU16  = (U_CNT + 15)/16;                    // 1250
  const int gI16  = (I_CNT + 15)/16;                    // 938
  const int gN16  = (N_CNT*16 + BS-1)/BS;
  const int gRu16 = (U_CNT*16 + BS-1)/BS;
  const int gRi16 = (I_CNT*16 + BS-1)/BS;
  const int gGu   = (U_CNT + 63)/64;                    // 313
  const int gGi   = (I_CNT + 63)/64;                    // 235
  const int gGr   = (ER + 63)/64;                       // 938
  const int gGa   = A_CNT/64;                           // 32

  // ---- linked-list build ----
  fill_m1<<<(int)((head_ints/4 + BS-1)/BS), BS, 0, stream>>>((int4*)ibase, (int)(head_ints/4));
  build_batched<<<dim3(gE, NLIST), BS, 0, stream>>>(bm);

  // ---- small precompute ----
  sigtab_kernel<<<8, BS, 0, stream>>>(rating_emb[0],rating_emb[1],rating_emb[2],
                                      rating_emb[3],rating_emb[4],rating_emb[5], sigt);
  fe1c_kernel<<<gN16, BS, 0, stream>>>(feature1, user_cui, item_ciu, fe1c);

  // ---- split-K count GEMMs + fused reduce/blend epilogue ----
  gemm_splitk<<<dim3(gGu, SPLIT), BS, 0, stream>>>(user_aspect_count, U_CNT, W_count_user, part_u);
  gemm_splitk<<<dim3(gGi, SPLIT), BS, 0, stream>>>(item_aspect_count, I_CNT, W_count_item, part_i);
  reduce_blend<<<gRu16, BS, 0, stream>>>(part_u, U_CNT, SPLIT, b_count_user,
      user_mask, user_cau, feature3, user_cui, g_u);
  reduce_blend<<<gRi16, BS, 0, stream>>>(part_i, I_CNT, SPLIT, b_count_item,
      item_mask, item_cai, feature3 + (size_t)U_CNT*64, item_ciu, g_i);

  // ---- K=64 GEMMs ----
  K64Meta km;
  km.A[0]=aspect_fe; km.W[0]=W_aspect;  km.mulp[0]=aspect_cau; km.C[0]=msg_au; km.M[0]=A_CNT;
  km.A[1]=aspect_fe; km.W[1]=W_aspect2; km.mulp[1]=aspect_cai; km.C[1]=msg_ai; km.M[1]=A_CNT;
  if (tierA) {
    for (int k = 0; k < 5; ++k) {
      km.A[2+k]=uiK_review[k]; km.W[2+k]=W_review1; km.mulp[2+k]=nullptr; km.C[2+k]=reb[k];   km.M[2+k]=ER;
      km.A[7+k]=iuK_review[k]; km.W[7+k]=W_review2; km.mulp[7+k]=nullptr; km.C[7+k]=reb[5+k]; km.M[7+k]=ER;
    }
    gemm_k64<<<dim3(gGr, 12), BS, 0, stream>>>(km);
  } else {
    gemm_k64<<<dim3(gGa, 2), BS, 0, stream>>>(km);
  }

  // ---- aspect gathers with blend epilogue ----
  gather_blend<<<gU16, BS, 0, stream>>>(bm.head[0], bm.node[0], msg_au,
      user_mask, user_cau, feature2, user_cui, h_u_a, U_CNT);
  gather_blend<<<gI16, BS, 0, stream>>>(bm.head[1], bm.node[1], msg_ai,
      item_mask, item_cai, feature2 + (size_t)U_CNT*64, item_ciu, h_i_a, I_CNT);

  // ---- fused 3-acc gathers -> outputs 1..3 ----
  gather3<<<gI16, BS, 0, stream>>>(bm.head[2], bm.node[2],
      h_u_a, g_u, fe1c, sigt + 0*320, sigt + 2*320, sigt + 4*320,
      item_ciu, out + (size_t)U_CNT*64, out2 + (size_t)U_CNT*64, out3 + (size_t)U_CNT*64, I_CNT);
  gather3<<<gU16, BS, 0, stream>>>(bm.head[3], bm.node[3],
      h_i_a, g_i, fe1c + (size_t)U_CNT*64, sigt + 1*320, sigt + 3*320, sigt + 5*320,
      user_cui, out, out2, out3, U_CNT);

  // ---- fe5/re branch ----
  auto fill_fe5 = [&](Fe5Meta& fm, int z, int k, const float* rebuf_ui, const float* rebuf_iu){
    fm.head[z]=bm.head[4+k]; fm.node[z]=bm.node[4+k];
    fm.re[z]=rebuf_ui; fm.w[z]=weightK[k]; fm.cuiS[z]=user_cuiK[k]; fm.cmulD[z]=item_ciuK[k];
    fm.outA[z]=out4 + (size_t)U_CNT*320 + (size_t)k*64;
    fm.outB[z]=out5 + (size_t)U_CNT*320 + (size_t)k*64;
    fm.nseg[z]=I_CNT;
    fm.head[z+1]=bm.head[9+k]; fm.node[z+1]=bm.node[9+k];
    fm.re[z+1]=rebuf_iu; fm.w[z+1]=weightK[k] + (size_t)U_CNT*64;
    fm.cuiS[z+1]=item_ciuK[k]; fm.cmulD[z+1]=user_cuiK[k];
    fm.outA[z+1]=out4 + (size_t)k*64;
    fm.outB[z+1]=out5 + (size_t)k*64;
    fm.nseg[z+1]=U_CNT;
  };

  if (tierA) {
    Fe5Meta fm;
    for (int k = 0; k < 5; ++k) fill_fe5(fm, 2*k, k, reb[k], reb[5+k]);
    gather_fe5_batched<<<dim3(gU16, 10), BS, 0, stream>>>(fm);
  } else {
    for (int k = 0; k < 5; ++k) {
      K64Meta kr;
      kr.A[0]=uiK_review[k]; kr.W[0]=W_review1; kr.mulp[0]=nullptr; kr.C[0]=reb[0]; kr.M[0]=ER;
      kr.A[1]=iuK_review[k]; kr.W[1]=W_review2; kr.mulp[1]=nullptr; kr.C[1]=reb[1]; kr.M[1]=ER;
      gemm_k64<<<dim3(gGr, 2), BS, 0, stream>>>(kr);
      Fe5Meta fm;
      fill_fe5(fm, 0, k, reb[0], reb[1]);
      gather_fe5_batched<<<dim3(gU16, 2), BS, 0, stream>>>(fm);
    }
  }
}

// Round 5
// 534.695 us; speedup vs baseline: 6.9324x; 1.0512x over previous
//
#include <hip/hip_runtime.h>
#include <cstddef>

#define U_CNT 20000
#define I_CNT 15000
#define N_CNT 35000
#define A_CNT 2048
#define NC_K  2048
#define EAU   300000
#define EUI   300000
#define ER    60000
#define NLIST 14

__device__ __forceinline__ float4 ld4(const float* p){ return *reinterpret_cast<const float4*>(p); }
__device__ __forceinline__ void st4(float* p, float4 v){ *reinterpret_cast<float4*>(p) = v; }
__device__ __forceinline__ float4 mul4(float4 a, float4 b){ return make_float4(a.x*b.x, a.y*b.y, a.z*b.z, a.w*b.w); }
__device__ __forceinline__ float4 add4(float4 a, float4 b){ return make_float4(a.x+b.x, a.y+b.y, a.z+b.z, a.w+b.w); }
__device__ __forceinline__ float4 fmas4(float s, float4 b, float4 c){
  return make_float4(fmaf(s,b.x,c.x), fmaf(s,b.y,c.y), fmaf(s,b.z,c.z), fmaf(s,b.w,c.w));
}

// Shared GEMM core: C-tile accumulate of A[r0:r0+64, k0base:k0base+kcount] @ W[.,64]
__device__ __forceinline__ void gemm_core(
    const float* __restrict__ A, int lda, int M, int r0,
    const float* __restrict__ W, int k0base, int kcount,
    float* __restrict__ smem, float4* accs)
{
  float (*As)[36] = (float (*)[36])smem;
  float (*Ws)[64] = (float (*)[64])(smem + 64*36);
  const int t = threadIdx.x;
  const int ty = t >> 4, tx = t & 15;
  float4 acc0 = make_float4(0,0,0,0), acc1 = acc0, acc2 = acc0, acc3 = acc0;
  for (int k0 = k0base; k0 < k0base + kcount; k0 += 32) {
    __syncthreads();
    #pragma unroll
    for (int i = 0; i < 2; ++i) {
      int f = t + i*256;
      int row = f >> 3, caa = (f & 7) << 2;
      float4 v = make_float4(0.f,0.f,0.f,0.f);
      int r = r0 + row;
      if (r < M) v = ld4(&A[(size_t)r*lda + k0 + caa]);
      st4(&As[row][caa], v);
      int kk = f >> 4, cb = (f & 15) << 2;
      st4(&Ws[kk][cb], ld4(&W[(size_t)(k0+kk)*64 + cb]));
    }
    __syncthreads();
    #pragma unroll
    for (int kk = 0; kk < 32; kk += 4) {
      float4 a0 = ld4(&As[ty*4+0][kk]);
      float4 a1 = ld4(&As[ty*4+1][kk]);
      float4 a2 = ld4(&As[ty*4+2][kk]);
      float4 a3 = ld4(&As[ty*4+3][kk]);
      float a0v[4] = {a0.x,a0.y,a0.z,a0.w};
      float a1v[4] = {a1.x,a1.y,a1.z,a1.w};
      float a2v[4] = {a2.x,a2.y,a2.z,a2.w};
      float a3v[4] = {a3.x,a3.y,a3.z,a3.w};
      #pragma unroll
      for (int j = 0; j < 4; ++j) {
        float4 wv = ld4(&Ws[kk+j][tx<<2]);
        acc0 = fmas4(a0v[j], wv, acc0);
        acc1 = fmas4(a1v[j], wv, acc1);
        acc2 = fmas4(a2v[j], wv, acc2);
        acc3 = fmas4(a3v[j], wv, acc3);
      }
    }
  }
  accs[0]=acc0; accs[1]=acc1; accs[2]=acc2; accs[3]=acc3;
}

// =================== MEGA1: fill + sigtab + fe1c + splitk + k64 ===================
struct Mega1Args {
  int e_fill, e_sig, e_fe1c, e_sp, split;
  int4* fillp; int fill_n4;
  const float* emb[6]; float* sigt;
  const float* f1; const float* cui; const float* ciu; float* fe1c;
  const float* spA[2]; const float* spW[2]; float* spPart[2]; int spM[2];
  const float* kA[12]; const float* kW[12]; const float* kMul[12]; float* kC[12]; int kM[12];
};

__global__ __launch_bounds__(256) void mega1(Mega1Args a)
{
  __shared__ float smem[64*36 + 32*64];
  int b = blockIdx.x, t = threadIdx.x;
  if (b < a.e_fill) {
    int gid = b*256 + t;
    if (gid < a.fill_n4) a.fillp[gid] = make_int4(-1,-1,-1,-1);
    return;
  }
  if (b < a.e_sig) {
    int gid = (b - a.e_fill)*256 + t;
    if (gid < 6*320) {
      int k = gid/320, j = gid%320;
      a.sigt[gid] = 1.f/(1.f + __expf(-a.emb[k][j]));
    }
    return;
  }
  if (b < a.e_fe1c) {
    int gid = (b - a.e_sig)*256 + t;
    if (gid < N_CNT*16) {
      int n = gid >> 4, q = (gid & 15) << 2;
      size_t o = (size_t)n*64 + q;
      float4 v = ld4(&a.f1[o]);
      float4 c = (n < U_CNT) ? ld4(&a.cui[o]) : ld4(&a.ciu[(size_t)(n-U_CNT)*64 + q]);
      st4(&a.fe1c[o], mul4(v, c));
    }
    return;
  }
  if (b < a.e_sp) {
    int local = b - a.e_fe1c;
    int z = local / 313, bx = local % 313;
    int side = z / a.split, sp = z % a.split;
    int M = a.spM[side];
    int r0 = bx*64;
    if (r0 >= M) return;
    int kchunk = NC_K / a.split;
    float4 accs[4];
    gemm_core(a.spA[side], NC_K, M, r0, a.spW[side], sp*kchunk, kchunk, smem, accs);
    float* base = a.spPart[side] + (size_t)sp * M * 64;
    int ty = t >> 4, tx = t & 15;
    #pragma unroll
    for (int i = 0; i < 4; ++i) {
      int r = r0 + ty*4 + i;
      if (r < M) st4(&base[(size_t)r*64 + (tx<<2)], accs[i]);
    }
    return;
  }
  {
    int local = b - a.e_sp;
    int z = local / 938, bx = local % 938;
    int M = a.kM[z];
    int r0 = bx*64;
    if (r0 >= M) return;
    float4 accs[4];
    gemm_core(a.kA[z], 64, M, r0, a.kW[z], 0, 64, smem, accs);
    const float* mulp = a.kMul[z];
    float* C = a.kC[z];
    int ty = t >> 4, tx = t & 15;
    #pragma unroll
    for (int i = 0; i < 4; ++i) {
      int r = r0 + ty*4 + i;
      if (r < M) {
        float4 v = accs[i];
        size_t o = (size_t)r*64 + (tx<<2);
        if (mulp) v = mul4(v, ld4(&mulp[o]));
        st4(&C[o], v);
      }
    }
  }
}

// =================== MEGA2: linked-list build + reduce_blend ===================
struct Mega2Args {
  int e_build, e_ru, split;
  const int* src[NLIST]; const int* dst[NLIST]; const int* rat[NLIST];
  int2* node[NLIST]; int* head[NLIST]; int E[NLIST];
  const float* part[2]; int M[2];
  const float* bias[2]; const float* mask[2];
  const float* ca[2]; const float* fe[2]; const float* cui[2]; float* outb[2];
};

__global__ __launch_bounds__(256) void mega2(Mega2Args a)
{
  int b = blockIdx.x, t = threadIdx.x;
  if (b < a.e_build) {
    int li = b / 1172;
    int i = (b % 1172)*256 + t;
    if (i < a.E[li]) {
      int d = a.dst[li][i];
      int pay = a.src[li][i];
      const int* rat = a.rat[li];
      if (rat) pay |= rat[i] << 20;
      int prev = atomicExch(&a.head[li][d], i);
      a.node[li][i] = make_int2(prev, pay);
    }
    return;
  }
  int side, gid;
  if (b < a.e_ru) { side = 0; gid = (b - a.e_build)*256 + t; }
  else            { side = 1; gid = (b - a.e_ru)*256 + t; }
  int M = a.M[side];
  if (gid >= M*16) return;
  int n = gid >> 4, q = (gid & 15) << 2;
  float4 acc = ld4(&a.bias[side][q]);
  const float* part = a.part[side];
  for (int s = 0; s < a.split; ++s)
    acc = add4(acc, ld4(&part[((size_t)s*M + n)*64 + q]));
  size_t o = (size_t)n*64 + q;
  float m = a.mask[side][n], im = 1.f - m;
  float4 cav = ld4(&a.ca[side][o]), fev = ld4(&a.fe[side][o]), cv = ld4(&a.cui[side][o]);
  st4(&a.outb[side][o], make_float4((m*(acc.x*cav.x) + im*fev.x)*cv.x,
                                    (m*(acc.y*cav.y) + im*fev.y)*cv.y,
                                    (m*(acc.z*cav.z) + im*fev.z)*cv.z,
                                    (m*(acc.w*cav.w) + im*fev.w)*cv.w));
}

// =================== MEGA3: aspect gather-blend + fe5/re gathers ===================
#define FE5Z 10
struct Mega3Args {
  int e_gbu, e_gbi;
  const int* gb_head[2]; const int2* gb_node[2];
  const float* gb_msg[2]; const float* gb_mask[2]; const float* gb_ca[2];
  const float* gb_fe[2]; const float* gb_cui[2]; float* gb_out[2]; int gb_n[2];
  const int* f_head[FE5Z]; const int2* f_node[FE5Z];
  const float* f_re[FE5Z]; const float* f_w[FE5Z]; const float* f_cui[FE5Z];
  const float* f_cmul[FE5Z]; float* f_outA[FE5Z]; float* f_outB[FE5Z]; int f_n[FE5Z];
};

__global__ __launch_bounds__(256) void mega3(Mega3Args a)
{
  int b = blockIdx.x, t = threadIdx.x;
  int q = (t & 15) << 2;
  if (b < a.e_gbi) {
    int side = (b >= a.e_gbu);
    int bx = side ? (b - a.e_gbu) : b;
    int d = bx*16 + (t >> 4);
    if (d >= a.gb_n[side]) return;
    const int2* __restrict__ node = a.gb_node[side];
    const float* __restrict__ msg = a.gb_msg[side];
    float4 acc = make_float4(0,0,0,0);
    for (int cur = a.gb_head[side][d]; cur >= 0; ) {
      int2 nd = node[cur];
      cur = nd.x;
      acc = add4(acc, ld4(&msg[(size_t)nd.y*64 + q]));
    }
    size_t o = (size_t)d*64 + q;
    float m = a.gb_mask[side][d], im = 1.f - m;
    float4 cav = ld4(&a.gb_ca[side][o]), fev = ld4(&a.gb_fe[side][o]), cv = ld4(&a.gb_cui[side][o]);
    st4(&a.gb_out[side][o], make_float4((m*(acc.x*cav.x) + im*fev.x)*cv.x,
                                        (m*(acc.y*cav.y) + im*fev.y)*cv.y,
                                        (m*(acc.z*cav.z) + im*fev.z)*cv.z,
                                        (m*(acc.w*cav.w) + im*fev.w)*cv.w));
    return;
  }
  {
    int local = b - a.e_gbi;
    int z = local / 1250, bx = local % 1250;
    int d = bx*16 + (t >> 4);
    if (d >= a.f_n[z]) return;
    const int2* __restrict__ node = a.f_node[z];
    const float* __restrict__ re = a.f_re[z];
    const float* __restrict__ w = a.f_w[z];
    const float* __restrict__ cuiS = a.f_cui[z];
    float4 a0 = make_float4(0,0,0,0), a1 = a0;
    for (int cur = a.f_head[z][d]; cur >= 0; ) {
      int2 nd = node[cur];
      int e = cur;
      cur = nd.x;
      int s = nd.y;
      float4 rv = ld4(&re[(size_t)e*64 + q]);
      float4 cv = ld4(&cuiS[(size_t)s*64 + q]);
      float4 wv = ld4(&w[(size_t)s*64 + q]);
      a0 = add4(a0, mul4(add4(wv, rv), cv));
      a1 = add4(a1, mul4(rv, cv));
    }
    float4 c = ld4(&a.f_cmul[z][(size_t)d*64 + q]);
    size_t o = (size_t)d*320 + q;
    st4(&a.f_outA[z][o], mul4(a0, c));
    st4(&a.f_outB[z][o], mul4(a1, c));
  }
}

// =================== MEGA4: fused 3-acc gathers ===================
struct Mega4Args {
  int e_g3i;
  const int* head[2]; const int2* node[2];
  const float* msgA[2]; const float* msgB[2]; const float* msgC[2];
  const float* sigA[2]; const float* sigB[2]; const float* sigC[2];
  const float* cmul[2]; float* outA[2]; float* outB[2]; float* outC[2]; int n[2];
};

__global__ __launch_bounds__(256) void mega4(Mega4Args a)
{
  int b = blockIdx.x, t = threadIdx.x;
  int side = (b >= a.e_g3i);
  int bx = side ? (b - a.e_g3i) : b;
  int d = bx*16 + (t >> 4);
  if (d >= a.n[side]) return;
  int q = (t & 15) << 2;
  const int2* __restrict__ node = a.node[side];
  const float* __restrict__ msgA = a.msgA[side];
  const float* __restrict__ msgB = a.msgB[side];
  const float* __restrict__ msgC = a.msgC[side];
  const float* __restrict__ sigA = a.sigA[side];
  const float* __restrict__ sigB = a.sigB[side];
  const float* __restrict__ sigC = a.sigC[side];
  float4 a0 = make_float4(0,0,0,0), a1 = a0, a2 = a0;
  for (int cur = a.head[side][d]; cur >= 0; ) {
    int2 nd = node[cur];
    cur = nd.x;
    int s = nd.y & 0xFFFFF;
    int r = nd.y >> 20;
    size_t so = (size_t)s*64 + q;
    int ro = r*64 + q;
    a0 = add4(a0, mul4(ld4(&msgA[so]), ld4(&sigA[ro])));
    a1 = add4(a1, mul4(ld4(&msgB[so]), ld4(&sigB[ro])));
    a2 = add4(a2, mul4(ld4(&msgC[so]), ld4(&sigC[ro])));
  }
  size_t o = (size_t)d*64 + q;
  float4 c = ld4(&a.cmul[side][o]);
  st4(&a.outA[side][o], mul4(a0, c));
  st4(&a.outB[side][o], mul4(a1, c));
  st4(&a.outC[side][o], mul4(a2, c));
}

extern "C" void kernel_launch(void* const* d_in, const int* in_sizes, int n_in,
                              void* d_out, int out_size, void* d_ws, size_t ws_size,
                              hipStream_t stream)
{
  (void)in_sizes; (void)n_in; (void)out_size;
  auto F = [&](int i){ return (const float*)d_in[i]; };
  auto Ix = [&](int i){ return (const int*)d_in[i]; };

  const float* feature1 = F(0);
  const float* feature2 = F(1);
  const float* feature3 = F(2);
  const float* weightK[5]   = {F(3),F(4),F(5),F(6),F(7)};
  const float* W_review1 = F(8);
  const float* W_review2 = F(9);
  const float* rating_emb[6] = {F(10),F(11),F(12),F(13),F(14),F(15)};
  const float* W_aspect  = F(16);
  const float* W_aspect2 = F(17);
  const float* W_count_user = F(18);
  const float* b_count_user = F(19);
  const float* W_count_item = F(20);
  const float* b_count_item = F(21);
  const float* aspect_fe  = F(22);
  const float* aspect_cau = F(23);
  const float* aspect_cai = F(24);
  const float* user_cau = F(25);
  const float* user_cui = F(26);
  const float* item_cai = F(27);
  const float* item_ciu = F(28);
  const float* user_cuiK[5] = {F(29),F(31),F(33),F(35),F(37)};
  const float* item_ciuK[5] = {F(30),F(32),F(34),F(36),F(38)};
  const float* user_mask = F(39);
  const float* item_mask = F(40);
  const float* user_aspect_count = F(41);
  const float* item_aspect_count = F(42);
  const float* uiK_review[5] = {F(45),F(47),F(49),F(51),F(53)};
  const float* iuK_review[5] = {F(46),F(48),F(50),F(52),F(54)};
  const int* au_src = Ix(55); const int* au_dst = Ix(56);
  const int* ai_src = Ix(57); const int* ai_dst = Ix(58);
  const int* ui_src = Ix(59); const int* ui_dst = Ix(60); const int* ui_rating = Ix(61);
  const int* iu_src = Ix(62); const int* iu_dst = Ix(63); const int* iu_rating = Ix(64);
  const int* uiK_src[5] = {Ix(65),Ix(69),Ix(73),Ix(77),Ix(81)};
  const int* uiK_dst[5] = {Ix(66),Ix(70),Ix(74),Ix(78),Ix(82)};
  const int* iuK_src[5] = {Ix(67),Ix(71),Ix(75),Ix(79),Ix(83)};
  const int* iuK_dst[5] = {Ix(68),Ix(72),Ix(76),Ix(80),Ix(84)};

  float* out  = (float*)d_out;
  float* out2 = out + (size_t)N_CNT*64;
  float* out3 = out + 2*(size_t)N_CNT*64;
  float* out4 = out + 3*(size_t)N_CNT*64;              // (N,320)
  float* out5 = out + 8*(size_t)N_CNT*64;              // (N,320)

  // ---- workspace layout ----
  float* ws = (float*)d_ws;
  size_t off = 0;
  auto alloc = [&](size_t n){ float* p = ws + off; off += (n + 3) & ~(size_t)3; return p; };
  float* sigt   = alloc(6*320);
  float* msg_au = alloc((size_t)A_CNT*64);
  float* msg_ai = alloc((size_t)A_CNT*64);
  float* h_u_a  = alloc((size_t)U_CNT*64);
  float* h_i_a  = alloc((size_t)I_CNT*64);
  float* g_u    = alloc((size_t)U_CNT*64);
  float* g_i    = alloc((size_t)I_CNT*64);
  float* fe1c   = alloc((size_t)N_CNT*64);

  const int* l_src[NLIST] = {au_src, ai_src, ui_src, iu_src,
                             uiK_src[0],uiK_src[1],uiK_src[2],uiK_src[3],uiK_src[4],
                             iuK_src[0],iuK_src[1],iuK_src[2],iuK_src[3],iuK_src[4]};
  const int* l_dst[NLIST] = {au_dst, ai_dst, ui_dst, iu_dst,
                             uiK_dst[0],uiK_dst[1],uiK_dst[2],uiK_dst[3],uiK_dst[4],
                             iuK_dst[0],iuK_dst[1],iuK_dst[2],iuK_dst[3],iuK_dst[4]};
  const int* l_rat[NLIST] = {nullptr, nullptr, ui_rating, iu_rating,
                             nullptr,nullptr,nullptr,nullptr,nullptr,
                             nullptr,nullptr,nullptr,nullptr,nullptr};
  int l_E[NLIST]    = {EAU,EAU,EUI,EUI, ER,ER,ER,ER,ER, ER,ER,ER,ER,ER};
  int l_nseg[NLIST] = {U_CNT,I_CNT,I_CNT,U_CNT, I_CNT,I_CNT,I_CNT,I_CNT,I_CNT,
                       U_CNT,U_CNT,U_CNT,U_CNT,U_CNT};

  int* ibase = (int*)(ws + off);
  int* lhead[NLIST]; int2* lnode[NLIST];
  size_t io = 0;
  for (int l = 0; l < NLIST; ++l) { lhead[l] = ibase + io; io += l_nseg[l]; }
  size_t head_ints = io;                                 // 245000
  for (int l = 0; l < NLIST; ++l) { lnode[l] = (int2*)(ibase + io); io += 2*(size_t)l_E[l]; }
  off += (io + 3) & ~(size_t)3;

  // part region + re region, NON-aliased (both written in MEGA1)
  const size_t reN = (size_t)ER*64;
  int SPLIT = 8;
  while (SPLIT > 1 && (off + (size_t)SPLIT*N_CNT*64 + 10*reN) * 4 > ws_size) SPLIT >>= 1;
  float* part_u = ws + off;
  float* part_i = part_u + (size_t)SPLIT*U_CNT*64;
  float* rebase = part_u + (size_t)SPLIT*N_CNT*64;
  float* reb[10];
  for (int j = 0; j < 10; ++j) reb[j] = rebase + (size_t)j*reN;

  // ---- MEGA1 ----
  Mega1Args a1;
  const int B_FILL = (int)((head_ints/4 + 255)/256);    // 240
  const int B_SIG  = 8;
  const int B_FE1C = (N_CNT*16 + 255)/256;              // 2188
  const int B_SP   = 2*SPLIT*313;
  const int B_K64  = 12*938;
  a1.e_fill = B_FILL;
  a1.e_sig  = B_FILL + B_SIG;
  a1.e_fe1c = a1.e_sig + B_FE1C;
  a1.e_sp   = a1.e_fe1c + B_SP;
  a1.split  = SPLIT;
  a1.fillp = (int4*)ibase; a1.fill_n4 = (int)(head_ints/4);
  for (int k = 0; k < 6; ++k) a1.emb[k] = rating_emb[k];
  a1.sigt = sigt;
  a1.f1 = feature1; a1.cui = user_cui; a1.ciu = item_ciu; a1.fe1c = fe1c;
  a1.spA[0] = user_aspect_count; a1.spW[0] = W_count_user; a1.spPart[0] = part_u; a1.spM[0] = U_CNT;
  a1.spA[1] = item_aspect_count; a1.spW[1] = W_count_item; a1.spPart[1] = part_i; a1.spM[1] = I_CNT;
  a1.kA[0]=aspect_fe; a1.kW[0]=W_aspect;  a1.kMul[0]=aspect_cau; a1.kC[0]=msg_au; a1.kM[0]=A_CNT;
  a1.kA[1]=aspect_fe; a1.kW[1]=W_aspect2; a1.kMul[1]=aspect_cai; a1.kC[1]=msg_ai; a1.kM[1]=A_CNT;
  for (int k = 0; k < 5; ++k) {
    a1.kA[2+k]=uiK_review[k]; a1.kW[2+k]=W_review1; a1.kMul[2+k]=nullptr; a1.kC[2+k]=reb[k];   a1.kM[2+k]=ER;
    a1.kA[7+k]=iuK_review[k]; a1.kW[7+k]=W_review2; a1.kMul[7+k]=nullptr; a1.kC[7+k]=reb[5+k]; a1.kM[7+k]=ER;
  }
  mega1<<<a1.e_sp + B_K64, 256, 0, stream>>>(a1);

  // ---- MEGA2 ----
  Mega2Args a2;
  const int B_BUILD = NLIST*1172;
  const int B_RU = (U_CNT*16 + 255)/256;                // 1250
  const int B_RI = (I_CNT*16 + 255)/256;                // 938
  a2.e_build = B_BUILD;
  a2.e_ru = B_BUILD + B_RU;
  a2.split = SPLIT;
  for (int l = 0; l < NLIST; ++l) {
    a2.src[l]=l_src[l]; a2.dst[l]=l_dst[l]; a2.rat[l]=l_rat[l];
    a2.node[l]=lnode[l]; a2.head[l]=lhead[l]; a2.E[l]=l_E[l];
  }
  a2.part[0]=part_u; a2.M[0]=U_CNT; a2.bias[0]=b_count_user; a2.mask[0]=user_mask;
  a2.ca[0]=user_cau; a2.fe[0]=feature3; a2.cui[0]=user_cui; a2.outb[0]=g_u;
  a2.part[1]=part_i; a2.M[1]=I_CNT; a2.bias[1]=b_count_item; a2.mask[1]=item_mask;
  a2.ca[1]=item_cai; a2.fe[1]=feature3 + (size_t)U_CNT*64; a2.cui[1]=item_ciu; a2.outb[1]=g_i;
  mega2<<<a2.e_ru + B_RI, 256, 0, stream>>>(a2);

  // ---- MEGA3 ----
  Mega3Args a3;
  const int B_GBU = (U_CNT + 15)/16;                    // 1250
  const int B_GBI = (I_CNT + 15)/16;                    // 938
  a3.e_gbu = B_GBU;
  a3.e_gbi = B_GBU + B_GBI;
  a3.gb_head[0]=lhead[0]; a3.gb_node[0]=lnode[0]; a3.gb_msg[0]=msg_au;
  a3.gb_mask[0]=user_mask; a3.gb_ca[0]=user_cau; a3.gb_fe[0]=feature2;
  a3.gb_cui[0]=user_cui; a3.gb_out[0]=h_u_a; a3.gb_n[0]=U_CNT;
  a3.gb_head[1]=lhead[1]; a3.gb_node[1]=lnode[1]; a3.gb_msg[1]=msg_ai;
  a3.gb_mask[1]=item_mask; a3.gb_ca[1]=item_cai; a3.gb_fe[1]=feature2 + (size_t)U_CNT*64;
  a3.gb_cui[1]=item_ciu; a3.gb_out[1]=h_i_a; a3.gb_n[1]=I_CNT;
  for (int k = 0; k < 5; ++k) {
    int z = 2*k;
    a3.f_head[z]=lhead[4+k]; a3.f_node[z]=lnode[4+k];
    a3.f_re[z]=reb[k]; a3.f_w[z]=weightK[k]; a3.f_cui[z]=user_cuiK[k]; a3.f_cmul[z]=item_ciuK[k];
    a3.f_outA[z]=out4 + (size_t)U_CNT*320 + (size_t)k*64;
    a3.f_outB[z]=out5 + (size_t)U_CNT*320 + (size_t)k*64;
    a3.f_n[z]=I_CNT;
    a3.f_head[z+1]=lhead[9+k]; a3.f_node[z+1]=lnode[9+k];
    a3.f_re[z+1]=reb[5+k]; a3.f_w[z+1]=weightK[k] + (size_t)U_CNT*64;
    a3.f_cui[z+1]=item_ciuK[k]; a3.f_cmul[z+1]=user_cuiK[k];
    a3.f_outA[z+1]=out4 + (size_t)k*64;
    a3.f_outB[z+1]=out5 + (size_t)k*64;
    a3.f_n[z+1]=U_CNT;
  }
  mega3<<<a3.e_gbi + FE5Z*1250, 256, 0, stream>>>(a3);

  // ---- MEGA4 ----
  Mega4Args a4;
  a4.e_g3i = B_GBI;                                     // ui-side (items) first: 938 blocks
  a4.head[0]=lhead[2]; a4.node[0]=lnode[2];
  a4.msgA[0]=h_u_a; a4.msgB[0]=g_u; a4.msgC[0]=fe1c;
  a4.sigA[0]=sigt + 0*320; a4.sigB[0]=sigt + 2*320; a4.sigC[0]=sigt + 4*320;
  a4.cmul[0]=item_ciu;
  a4.outA[0]=out + (size_t)U_CNT*64; a4.outB[0]=out2 + (size_t)U_CNT*64; a4.outC[0]=out3 + (size_t)U_CNT*64;
  a4.n[0]=I_CNT;
  a4.head[1]=lhead[3]; a4.node[1]=lnode[3];
  a4.msgA[1]=h_i_a; a4.msgB[1]=g_i; a4.msgC[1]=fe1c + (size_t)U_CNT*64;
  a4.sigA[1]=sigt + 1*320; a4.sigB[1]=sigt + 3*320; a4.sigC[1]=sigt + 5*320;
  a4.cmul[1]=user_cui;
  a4.outA[1]=out; a4.outB[1]=out2; a4.outC[1]=out3;
  a4.n[1]=U_CNT;
  mega4<<<B_GBI + B_GBU, 256, 0, stream>>>(a4);
}